// Round 9
// baseline (1566.758 us; speedup 1.0000x reference)
//
#include <hip/hip_runtime.h>
#include <math.h>

// ---------------- problem sizes ----------------
#define BATCH   1024
#define NCAND   100000
#define NCPAD   100032
#define DM      128
#define DB      256
#define NNUM    64
#define CTXS    96
#define NPAIR   (BATCH*CTXS)   // 98304
#define RCH     128
#define EMCAP   8192
#define BCAP    1024
#define NSAMP   1563
#define SAMPP   1600

// ---------------- workspace offsets (in floats) ----------------
#define WB_IN       0u
#define WB_E1       8192u
#define WB_E2       40960u
#define WB_K        73728u
#define WB_T1       90112u
#define WB_T2       122880u
#define WT_P1       155648u
#define WT_P2       188416u
#define OFF_CKH     221184u      // 100032*128 bf16 hi
#define OFF_CKL     6623232u     // 100032*128 bf16 lo
#define OFF_CANDN   13025280u    // 100000
#define OFF_KB      13125280u    // 1024*128
#define OFF_X2B     13387424u    // 1024*128
#define OFF_LNB     13518496u    // 1024*128
#define OFF_HB      13649568u    // 1024*256
#define OFF_XPRED   13911712u
#define OFF_XFIN    14042784u
#define OFF_KBA     14173856u    // kbAh 131072 shorts + kbAl 131072 shorts
#define OFF_PROBS   15743648u
#define OFF_TIDX    15841952u
#define OFF_YG      15940256u
#define OFF_SX      16038560u    // sims buffer (12.8M) / t-net t2
#define OFF_EV      28838560u
#define OFF_EI      29887136u
#define OFF_GCNT    30935712u
#define OFF_GTHR    30935840u
#define OFF_SAMP    30935968u    // 128*1600 floats

typedef __attribute__((ext_vector_type(8))) short bf16x8;
typedef __attribute__((ext_vector_type(4))) float f32x4;
#define MFMA16(A,B,C) C = __builtin_amdgcn_mfma_f32_16x16x32_bf16(A, B, C, 0, 0, 0)

__device__ __forceinline__ unsigned short f2bf(float x) {
  unsigned u = __float_as_uint(x);
  unsigned r = (u + 0x7FFFu + ((u >> 16) & 1u)) >> 16;
  return (unsigned short)r;
}
__device__ __forceinline__ float bf2f(unsigned short h) {
  return __uint_as_float(((unsigned)h) << 16);
}

// ---------------- prep ----------------
__global__ void __launch_bounds__(256) k_transpose(
    const float* __restrict__ w0, const float* __restrict__ w1,
    float* __restrict__ dst)
{
  const float* src[2] = {w0,w1};
  const int nn[2]  = {256,128};
  const int kkv[2] = {128,256};
  const int off[2] = {155648,188416};
  int stride = gridDim.x*blockDim.x;
  int t0 = blockIdx.x*blockDim.x + threadIdx.x;
#pragma unroll
  for (int m = 0; m < 2; ++m) {
    int total = nn[m]*kkv[m];
    for (int i = t0; i < total; i += stride) {
      int k = i / nn[m];
      int n = i - k*nn[m];
      dst[off[m] + i] = src[m][n*kkv[m] + k];
    }
  }
}

__global__ void __launch_bounds__(256) k_cvt_w(
    const float* __restrict__ w_in, const float* __restrict__ e1,
    const float* __restrict__ e2, const float* __restrict__ wk,
    const float* __restrict__ t1, const float* __restrict__ t2,
    unsigned short* __restrict__ Wh, unsigned short* __restrict__ Wl)
{
  const float* src[6] = {w_in, e1, e2, wk, t1, t2};
  const int tot[6] = {8192, 32768, 32768, 16384, 32768, 32768};
  const int off[6] = {WB_IN, WB_E1, WB_E2, WB_K, WB_T1, WB_T2};
  int stride = gridDim.x*blockDim.x;
  int t0 = blockIdx.x*blockDim.x + threadIdx.x;
#pragma unroll
  for (int m = 0; m < 6; ++m) {
    for (int i = t0; i < tot[m]; i += stride) {
      float x = src[m][i];
      unsigned short h = f2bf(x);
      Wh[off[m]+i] = h;
      Wl[off[m]+i] = f2bf(x - bf2f(h));
    }
  }
}

__global__ void __launch_bounds__(256) k_pad_ck(
    unsigned short* __restrict__ ckh, unsigned short* __restrict__ ckl)
{
  int i = blockIdx.x*256 + threadIdx.x;
  if (i < 4096) {
    ckh[(size_t)NCAND*128 + i] = 0;
    ckl[(size_t)NCAND*128 + i] = 0;
  }
}

__global__ void __launch_bounds__(256) k_cvt_kbA(
    const float* __restrict__ kb,
    unsigned short* __restrict__ kbAh, unsigned short* __restrict__ kbAl)
{
  int i = blockIdx.x*256 + threadIdx.x;
  int j = i & 7, lane = (i >> 3) & 63, s = (i >> 9) & 3, mt = (i >> 11) & 7, ch = i >> 14;
  int row = ch*128 + mt*16 + (lane & 15);
  int k = s*32 + (lane >> 4)*8 + j;
  float x = kb[(size_t)row*128 + k];
  unsigned short h = f2bf(x);
  kbAh[i] = h;
  kbAl[i] = f2bf(x - bf2f(h));
}

// ---------------- FUSED ENCODER v3: barrier-free, 64 rows/block, 32KB LDS ----------------
// Per wave: 16 rows, one 8KB wave-private buffer reused xnum -> x-frags -> H -> ln.
// Residual x kept in registers (xc). No __syncthreads anywhere.
template<bool BATCHOUT>
__global__ void __launch_bounds__(256) k_enc_fused(
    const float* __restrict__ xnum,
    const unsigned short* __restrict__ Wh, const unsigned short* __restrict__ Wl,
    const float* __restrict__ b_in, const float* __restrict__ b1,
    const float* __restrict__ b2, const float* __restrict__ mix_g,
    const float* __restrict__ mix_b, const float* __restrict__ b_k,
    unsigned short* __restrict__ ckh, unsigned short* __restrict__ ckl,
    float* __restrict__ candn,
    float* __restrict__ x2out, float* __restrict__ kout,
    int M)
{
  __shared__ __align__(16) unsigned short sBuf[16384];   // 4 waves x 4096 shorts
  const int tid = threadIdx.x;
  const int wv = tid >> 6, lane = tid & 63;
  const int q = lane >> 4, n16 = lane & 15;
  const int r0 = blockIdx.x * 64;
  unsigned short* wbuf = sBuf + wv*4096;
  float* xtw = (float*)wbuf;   // 16 rows x 68 floats

  // phase 0: stage own 16 rows of xnum (wave-private)
#pragma unroll
  for (int t = 0; t < 4; ++t) {
    int i = t*64 + lane;
    int row = i >> 4, c4 = i & 15;
    int gr = r0 + wv*16 + row;
    float4 v = {0.f,0.f,0.f,0.f};
    if (gr < M) v = *(const float4*)&xnum[(size_t)gr*64 + c4*4];
    *(float4*)&xtw[row*68 + c4*4] = v;
  }

  // phase 1: x = xnum @ W_in^T + b_in  (hi/lo x, hi/lo W)
  f32x4 xc[8];
#pragma unroll
  for (int nt = 0; nt < 8; ++nt) {
    float b = b_in[nt*16 + n16];
    xc[nt][0]=b; xc[nt][1]=b; xc[nt][2]=b; xc[nt][3]=b;
  }
#pragma unroll
  for (int ks = 0; ks < 2; ++ks) {
    bf16x8 ah, al;
    {
      const float* p = &xtw[n16*68 + ks*32 + q*8];
      float4 p0 = *(const float4*)p;
      float4 p1 = *(const float4*)(p+4);
#define CV(di, val) { unsigned short hh = f2bf(val); ah[di] = (short)hh; al[di] = (short)f2bf((val) - bf2f(hh)); }
      CV(0,p0.x) CV(1,p0.y) CV(2,p0.z) CV(3,p0.w) CV(4,p1.x) CV(5,p1.y) CV(6,p1.z) CV(7,p1.w)
#undef CV
    }
#pragma unroll
    for (int nt = 0; nt < 8; ++nt) {
      size_t wo = WB_IN + (size_t)(nt*16 + n16)*64 + ks*32 + q*8;
      bf16x8 bh = *(const bf16x8*)(Wh + wo);
      bf16x8 bl = *(const bf16x8*)(Wl + wo);
      MFMA16(ah, bh, xc[nt]); MFMA16(al, bh, xc[nt]); MFMA16(ah, bl, xc[nt]);
    }
  }

  // phase 2: x -> A-frags hi/lo in own buf (hi [0..2047], lo [2048..4095])
#pragma unroll
  for (int nt = 0; nt < 8; ++nt) {
    int col = nt*16 + n16;
    int ks2 = col >> 5, q2 = (col >> 3) & 3, j2 = col & 7;
#pragma unroll
    for (int i = 0; i < 4; ++i) {
      int idx = ks2*512 + (q2*16 + q*4 + i)*8 + j2;
      float v = xc[nt][i];
      unsigned short hh = f2bf(v);
      wbuf[idx] = hh;
      wbuf[2048 + idx] = f2bf(v - bf2f(hh));
    }
  }

  // phase 3: H = relu(x @ E1^T + b1)
  f32x4 hc[16];
#pragma unroll
  for (int nt = 0; nt < 16; ++nt) { hc[nt][0]=0.f; hc[nt][1]=0.f; hc[nt][2]=0.f; hc[nt][3]=0.f; }
#pragma unroll
  for (int ks = 0; ks < 4; ++ks) {
    bf16x8 ah = *(const bf16x8*)(wbuf + ks*512 + lane*8);
    bf16x8 al = *(const bf16x8*)(wbuf + 2048 + ks*512 + lane*8);
#pragma unroll
    for (int nt = 0; nt < 16; ++nt) {
      size_t wo = WB_E1 + (size_t)(nt*16 + n16)*128 + ks*32 + q*8;
      bf16x8 bh = *(const bf16x8*)(Wh + wo);
      bf16x8 bl = *(const bf16x8*)(Wl + wo);
      MFMA16(ah, bh, hc[nt]); MFMA16(al, bh, hc[nt]); MFMA16(ah, bl, hc[nt]);
    }
  }
  // H (single bf16) -> own buf, frames 0..7
#pragma unroll
  for (int nt = 0; nt < 16; ++nt) {
    float b = b1[nt*16 + n16];
    int col = nt*16 + n16;
    int ks2 = col >> 5, q2 = (col >> 3) & 3, j2 = col & 7;
#pragma unroll
    for (int i = 0; i < 4; ++i) {
      float v = fmaxf(hc[nt][i] + b, 0.f);
      wbuf[ks2*512 + (q2*16 + q*4 + i)*8 + j2] = f2bf(v);
    }
  }

  // phase 4: x2 = x + H @ E2^T + b2  (residual from xc registers)
  f32x4 x2c[8];
#pragma unroll
  for (int nt = 0; nt < 8; ++nt) { x2c[nt][0]=0.f; x2c[nt][1]=0.f; x2c[nt][2]=0.f; x2c[nt][3]=0.f; }
#pragma unroll
  for (int ks = 0; ks < 8; ++ks) {
    bf16x8 ha = *(const bf16x8*)(wbuf + ks*512 + lane*8);
#pragma unroll
    for (int nt = 0; nt < 8; ++nt) {
      size_t wo = WB_E2 + (size_t)(nt*16 + n16)*256 + ks*32 + q*8;
      bf16x8 bh = *(const bf16x8*)(Wh + wo);
      bf16x8 bl = *(const bf16x8*)(Wl + wo);
      MFMA16(ha, bh, x2c[nt]); MFMA16(ha, bl, x2c[nt]);
    }
  }
#pragma unroll
  for (int nt = 0; nt < 8; ++nt) {
    float b = b2[nt*16 + n16];
#pragma unroll
    for (int i = 0; i < 4; ++i) x2c[nt][i] += b + xc[nt][i];
  }
  if constexpr (BATCHOUT) {
#pragma unroll
    for (int nt = 0; nt < 8; ++nt) {
      int col = nt*16 + n16;
#pragma unroll
      for (int i = 0; i < 4; ++i) {
        int row = r0 + wv*16 + q*4 + i;
        if (row < M) x2out[(size_t)row*128 + col] = x2c[nt][i];
      }
    }
  }

  // phase 5: LayerNorm (16-lane shuffle reduce), write ln hi/lo frags to own buf
#pragma unroll
  for (int i = 0; i < 4; ++i) {
    float s = 0.f;
#pragma unroll
    for (int nt = 0; nt < 8; ++nt) s += x2c[nt][i];
    s += __shfl_xor(s, 1); s += __shfl_xor(s, 2); s += __shfl_xor(s, 4); s += __shfl_xor(s, 8);
    float mu = s * (1.f/128.f);
    float v = 0.f;
#pragma unroll
    for (int nt = 0; nt < 8; ++nt) { float d = x2c[nt][i] - mu; v += d*d; }
    v += __shfl_xor(v, 1); v += __shfl_xor(v, 2); v += __shfl_xor(v, 4); v += __shfl_xor(v, 8);
    float rs = rsqrtf(v*(1.f/128.f) + 1e-5f);
#pragma unroll
    for (int nt = 0; nt < 8; ++nt) {
      float lv = (x2c[nt][i] - mu)*rs*mix_g[nt*16 + n16] + mix_b[nt*16 + n16];
      int col = nt*16 + n16;
      int ks2 = col >> 5, q2 = (col >> 3) & 3, j2 = col & 7;
      int idx = ks2*512 + (q2*16 + q*4 + i)*8 + j2;
      unsigned short hh = f2bf(lv);
      wbuf[idx] = hh;
      wbuf[2048 + idx] = f2bf(lv - bf2f(hh));
    }
  }

  // phase 6: k = ln @ W_k^T + b_k
  f32x4 kc[8];
#pragma unroll
  for (int nt = 0; nt < 8; ++nt) {
    float b = b_k[nt*16 + n16];
    kc[nt][0]=b; kc[nt][1]=b; kc[nt][2]=b; kc[nt][3]=b;
  }
#pragma unroll
  for (int ks = 0; ks < 4; ++ks) {
    bf16x8 ah = *(const bf16x8*)(wbuf + ks*512 + lane*8);
    bf16x8 al = *(const bf16x8*)(wbuf + 2048 + ks*512 + lane*8);
#pragma unroll
    for (int nt = 0; nt < 8; ++nt) {
      size_t wo = WB_K + (size_t)(nt*16 + n16)*128 + ks*32 + q*8;
      bf16x8 bh = *(const bf16x8*)(Wh + wo);
      bf16x8 bl = *(const bf16x8*)(Wl + wo);
      MFMA16(ah, bh, kc[nt]); MFMA16(al, bh, kc[nt]); MFMA16(ah, bl, kc[nt]);
    }
  }

  // phase 7: outputs
#pragma unroll
  for (int i = 0; i < 4; ++i) {
    int row = r0 + wv*16 + q*4 + i;
    if constexpr (!BATCHOUT) {
      float s2 = 0.f;
#pragma unroll
      for (int nt = 0; nt < 8; ++nt) { float kv = kc[nt][i]; s2 += kv*kv; }
      s2 += __shfl_xor(s2, 1); s2 += __shfl_xor(s2, 2); s2 += __shfl_xor(s2, 4); s2 += __shfl_xor(s2, 8);
      if (n16 == 0 && row < M) candn[row] = s2;
    }
#pragma unroll
    for (int nt = 0; nt < 8; ++nt) {
      int col = nt*16 + n16;
      float kv = kc[nt][i];
      if (row < M) {
        if constexpr (BATCHOUT) {
          kout[(size_t)row*128 + col] = kv;
        } else {
          unsigned short hh = f2bf(kv);
          ckh[(size_t)row*128 + col] = hh;
          ckl[(size_t)row*128 + col] = f2bf(kv - bf2f(hh));
        }
      }
    }
  }
}

// ---------------- FUSED T-NET v2: barrier-free, 64 pairs/block, 32KB LDS ----------------
__global__ void __launch_bounds__(256) k_tnet(
    const float* __restrict__ kb,
    const unsigned short* __restrict__ ckh, const unsigned short* __restrict__ ckl,
    const int* __restrict__ tidxg,
    const unsigned short* __restrict__ Wh, const unsigned short* __restrict__ Wl,
    const float* __restrict__ b_t1, float* __restrict__ t2out)
{
  __shared__ __align__(16) unsigned short sBuf[16384];
  const int tid = threadIdx.x;
  const int wv = tid >> 6, lane = tid & 63;
  const int q = lane >> 4, n16 = lane & 15;
  const int p0 = blockIdx.x * 64;
  unsigned short* wbuf = sBuf + wv*4096;

  // gather + diff -> A-frag (single bf16), frames 0..3, wave-private
#pragma unroll
  for (int ks = 0; ks < 4; ++ks) {
    int m = lane & 15, qq = lane >> 4;
    int gp = p0 + wv*16 + m;
    int d  = ks*32 + qq*8;
    int idx = tidxg[gp];
    int bb  = gp / 96;
    bf16x8 h8 = *(const bf16x8*)(ckh + (size_t)idx*128 + d);
    bf16x8 l8 = *(const bf16x8*)(ckl + (size_t)idx*128 + d);
    float4 k0 = *(const float4*)&kb[(size_t)bb*128 + d];
    float4 k1 = *(const float4*)&kb[(size_t)bb*128 + d + 4];
    bf16x8 df;
    df[0] = (short)f2bf(k0.x - (bf2f(h8[0]) + bf2f(l8[0])));
    df[1] = (short)f2bf(k0.y - (bf2f(h8[1]) + bf2f(l8[1])));
    df[2] = (short)f2bf(k0.z - (bf2f(h8[2]) + bf2f(l8[2])));
    df[3] = (short)f2bf(k0.w - (bf2f(h8[3]) + bf2f(l8[3])));
    df[4] = (short)f2bf(k1.x - (bf2f(h8[4]) + bf2f(l8[4])));
    df[5] = (short)f2bf(k1.y - (bf2f(h8[5]) + bf2f(l8[5])));
    df[6] = (short)f2bf(k1.z - (bf2f(h8[6]) + bf2f(l8[6])));
    df[7] = (short)f2bf(k1.w - (bf2f(h8[7]) + bf2f(l8[7])));
    *(bf16x8*)(wbuf + ks*512 + lane*8) = df;
  }

  // T1
  f32x4 hc[16];
#pragma unroll
  for (int nt = 0; nt < 16; ++nt) { hc[nt][0]=0.f; hc[nt][1]=0.f; hc[nt][2]=0.f; hc[nt][3]=0.f; }
#pragma unroll
  for (int ks = 0; ks < 4; ++ks) {
    bf16x8 ad = *(const bf16x8*)(wbuf + ks*512 + lane*8);
#pragma unroll
    for (int nt = 0; nt < 16; ++nt) {
      size_t wo = WB_T1 + (size_t)(nt*16 + n16)*128 + ks*32 + q*8;
      bf16x8 bh = *(const bf16x8*)(Wh + wo);
      bf16x8 bl = *(const bf16x8*)(Wl + wo);
      MFMA16(ad, bh, hc[nt]); MFMA16(ad, bl, hc[nt]);
    }
  }
  // H -> own buf frames 0..7
#pragma unroll
  for (int nt = 0; nt < 16; ++nt) {
    float b = b_t1[nt*16 + n16];
    int col = nt*16 + n16;
    int ks2 = col >> 5, q2 = (col >> 3) & 3, j2 = col & 7;
#pragma unroll
    for (int i = 0; i < 4; ++i) {
      float v = fmaxf(hc[nt][i] + b, 0.f);
      wbuf[ks2*512 + (q2*16 + q*4 + i)*8 + j2] = f2bf(v);
    }
  }

  // T2
  f32x4 tc[8];
#pragma unroll
  for (int nt = 0; nt < 8; ++nt) { tc[nt][0]=0.f; tc[nt][1]=0.f; tc[nt][2]=0.f; tc[nt][3]=0.f; }
#pragma unroll
  for (int ks = 0; ks < 8; ++ks) {
    bf16x8 ha = *(const bf16x8*)(wbuf + ks*512 + lane*8);
#pragma unroll
    for (int nt = 0; nt < 8; ++nt) {
      size_t wo = WB_T2 + (size_t)(nt*16 + n16)*256 + ks*32 + q*8;
      bf16x8 bh = *(const bf16x8*)(Wh + wo);
      bf16x8 bl = *(const bf16x8*)(Wl + wo);
      MFMA16(ha, bh, tc[nt]); MFMA16(ha, bl, tc[nt]);
    }
  }
#pragma unroll
  for (int nt = 0; nt < 8; ++nt) {
    int col = nt*16 + n16;
#pragma unroll
    for (int i = 0; i < 4; ++i) {
      int pr = p0 + wv*16 + q*4 + i;
      t2out[(size_t)pr*128 + col] = tc[nt][i];
    }
  }
}

// ---------------- generic fp32 GEMM (predictor) ----------------
template<int N, bool RELU, bool RESID>
__global__ void __launch_bounds__(256) k_gemm(
    const float* __restrict__ A, const float* __restrict__ WT,
    const float* __restrict__ bias, const float* __restrict__ resid,
    float* __restrict__ C, int M, int K)
{
  constexpr int G = N/64;
  __shared__ __align__(16) float sA[64*33];
  __shared__ __align__(16) float sW[32*N];
  const int tid = threadIdx.x;
  const int r0 = blockIdx.x*64;
  const int tr = tid >> 4, tc = tid & 15;
  float acc[4][G*4];
#pragma unroll
  for (int i = 0; i < 4; ++i)
#pragma unroll
    for (int j = 0; j < G*4; ++j) acc[i][j] = 0.f;

  for (int kc = 0; kc < K; kc += 32) {
    for (int i = tid; i < 64*32; i += 256) {
      int r = i >> 5, kk = i & 31;
      int gr = r0 + r;
      sA[r*33 + kk] = (gr < M) ? A[(size_t)gr*K + kc + kk] : 0.f;
    }
    for (int i = tid; i < 32*N; i += 256) sW[i] = WT[(size_t)kc*N + i];
    __syncthreads();
    for (int kk = 0; kk < 32; ++kk) {
      float a0 = sA[(tr*4+0)*33+kk];
      float a1 = sA[(tr*4+1)*33+kk];
      float a2 = sA[(tr*4+2)*33+kk];
      float a3 = sA[(tr*4+3)*33+kk];
#pragma unroll
      for (int g = 0; g < G; ++g) {
        float4 w = *(const float4*)&sW[kk*N + g*64 + tc*4];
        acc[0][g*4+0] += a0*w.x; acc[0][g*4+1] += a0*w.y; acc[0][g*4+2] += a0*w.z; acc[0][g*4+3] += a0*w.w;
        acc[1][g*4+0] += a1*w.x; acc[1][g*4+1] += a1*w.y; acc[1][g*4+2] += a1*w.z; acc[1][g*4+3] += a1*w.w;
        acc[2][g*4+0] += a2*w.x; acc[2][g*4+1] += a2*w.y; acc[2][g*4+2] += a2*w.z; acc[2][g*4+3] += a2*w.w;
        acc[3][g*4+0] += a3*w.x; acc[3][g*4+1] += a3*w.y; acc[3][g*4+2] += a3*w.z; acc[3][g*4+3] += a3*w.w;
      }
    }
    __syncthreads();
  }

#pragma unroll
  for (int i = 0; i < 4; ++i) {
    int r = r0 + tr*4 + i;
    if (r < M) {
#pragma unroll
      for (int g = 0; g < G; ++g) {
        int col = g*64 + tc*4;
        float v0 = acc[i][g*4+0], v1 = acc[i][g*4+1], v2 = acc[i][g*4+2], v3 = acc[i][g*4+3];
        if (bias) { v0 += bias[col+0]; v1 += bias[col+1]; v2 += bias[col+2]; v3 += bias[col+3]; }
        if constexpr (RELU) { v0 = fmaxf(v0,0.f); v1 = fmaxf(v1,0.f); v2 = fmaxf(v2,0.f); v3 = fmaxf(v3,0.f); }
        if constexpr (RESID) {
          float4 rv = *(const float4*)&resid[(size_t)r*N + col];
          v0 += rv.x; v1 += rv.y; v2 += rv.z; v3 += rv.w;
        }
        float4 o4; o4.x = v0; o4.y = v1; o4.z = v2; o4.w = v3;
        *(float4*)&C[(size_t)r*N + col] = o4;
      }
    }
  }
}

// ---------------- LayerNorm (predictor prenorm) ----------------
__global__ void __launch_bounds__(256) k_ln(
    const float* __restrict__ x, const float* __restrict__ g, const float* __restrict__ b,
    float* __restrict__ o, int M)
{
  const int lane = threadIdx.x & 63, w = threadIdx.x >> 6;
  int rb = blockIdx.x*32 + w*8;
  for (int it = 0; it < 8; ++it) {
    int r = rb + it;
    if (r >= M) return;
    float a = x[(size_t)r*128 + lane];
    float c = x[(size_t)r*128 + 64 + lane];
    float s = a + c;
    for (int o2 = 32; o2; o2 >>= 1) s += __shfl_xor(s, o2);
    float mu = s * (1.f/128.f);
    float da = a - mu, dc = c - mu;
    float v = da*da + dc*dc;
    for (int o2 = 32; o2; o2 >>= 1) v += __shfl_xor(v, o2);
    float rs = rsqrtf(v*(1.f/128.f) + 1e-5f);
    o[(size_t)r*128 + lane]      = da*rs*g[lane]    + b[lane];
    o[(size_t)r*128 + 64 + lane] = dc*rs*g[lane+64] + b[lane+64];
  }
}

// ---------------- sims via MFMA (+ fused sample-column write) ----------------
__global__ void __launch_bounds__(256) k_sims_mfma(
    const unsigned short* __restrict__ kbAh, const unsigned short* __restrict__ kbAl,
    const unsigned short* __restrict__ ckh,  const unsigned short* __restrict__ ckl,
    const float* __restrict__ candn,
    float* __restrict__ sims, float* __restrict__ samp, int ch)
{
  const int tid = threadIdx.x;
  const int wv = tid >> 6, lane = tid & 63;
  const int c0 = blockIdx.x * 64;
  const int q = lane >> 4, n16 = lane & 15;

  f32x4 acc00 = {0.f,0.f,0.f,0.f}, acc01 = {0.f,0.f,0.f,0.f};
  f32x4 acc02 = {0.f,0.f,0.f,0.f}, acc03 = {0.f,0.f,0.f,0.f};
  f32x4 acc10 = {0.f,0.f,0.f,0.f}, acc11 = {0.f,0.f,0.f,0.f};
  f32x4 acc12 = {0.f,0.f,0.f,0.f}, acc13 = {0.f,0.f,0.f,0.f};

  const int mt0 = wv*2, mt1 = wv*2 + 1;
  const size_t a0base = (size_t)(ch*8 + mt0)*2048;
  const size_t a1base = (size_t)(ch*8 + mt1)*2048;
  const size_t b0 = (size_t)(c0 + n16)*128;
  const size_t b1 = b0 + 16*128;
  const size_t b2 = b0 + 32*128;
  const size_t b3 = b0 + 48*128;

#pragma unroll
  for (int s = 0; s < 4; ++s) {
    const size_t ao = (size_t)s*512 + (size_t)lane*8;
    bf16x8 ah0 = *(const bf16x8*)(kbAh + a0base + ao);
    bf16x8 ah1 = *(const bf16x8*)(kbAh + a1base + ao);
    bf16x8 al0 = *(const bf16x8*)(kbAl + a0base + ao);
    bf16x8 al1 = *(const bf16x8*)(kbAl + a1base + ao);
    const int ko = s*32 + q*8;
    bf16x8 bh0v = *(const bf16x8*)(ckh + b0 + ko);
    bf16x8 bh1v = *(const bf16x8*)(ckh + b1 + ko);
    bf16x8 bh2v = *(const bf16x8*)(ckh + b2 + ko);
    bf16x8 bh3v = *(const bf16x8*)(ckh + b3 + ko);
    bf16x8 bl0v = *(const bf16x8*)(ckl + b0 + ko);
    bf16x8 bl1v = *(const bf16x8*)(ckl + b1 + ko);
    bf16x8 bl2v = *(const bf16x8*)(ckl + b2 + ko);
    bf16x8 bl3v = *(const bf16x8*)(ckl + b3 + ko);

    MFMA16(ah0, bh0v, acc00); MFMA16(ah0, bh1v, acc01);
    MFMA16(ah0, bh2v, acc02); MFMA16(ah0, bh3v, acc03);
    MFMA16(ah1, bh0v, acc10); MFMA16(ah1, bh1v, acc11);
    MFMA16(ah1, bh2v, acc12); MFMA16(ah1, bh3v, acc13);

    MFMA16(al0, bh0v, acc00); MFMA16(al0, bh1v, acc01);
    MFMA16(al0, bh2v, acc02); MFMA16(al0, bh3v, acc03);
    MFMA16(al1, bh0v, acc10); MFMA16(al1, bh1v, acc11);
    MFMA16(al1, bh2v, acc12); MFMA16(al1, bh3v, acc13);

    MFMA16(ah0, bl0v, acc00); MFMA16(ah0, bl1v, acc01);
    MFMA16(ah0, bl2v, acc02); MFMA16(ah0, bl3v, acc03);
    MFMA16(ah1, bl0v, acc10); MFMA16(ah1, bl1v, acc11);
    MFMA16(ah1, bl2v, acc12); MFMA16(ah1, bl3v, acc13);
  }

  const int rb0 = mt0*16 + q*4, rb1 = mt1*16 + q*4;
#define EPI(NT, A0, A1) { \
    int col = c0 + NT*16 + n16; \
    if (col < NCAND) { \
      float cn = candn[col]; \
      sims[(size_t)(rb0+0)*NCAND + col] = 2.f*A0[0] - cn; \
      sims[(size_t)(rb0+1)*NCAND + col] = 2.f*A0[1] - cn; \
      sims[(size_t)(rb0+2)*NCAND + col] = 2.f*A0[2] - cn; \
      sims[(size_t)(rb0+3)*NCAND + col] = 2.f*A0[3] - cn; \
      sims[(size_t)(rb1+0)*NCAND + col] = 2.f*A1[0] - cn; \
      sims[(size_t)(rb1+1)*NCAND + col] = 2.f*A1[1] - cn; \
      sims[(size_t)(rb1+2)*NCAND + col] = 2.f*A1[2] - cn; \
      sims[(size_t)(rb1+3)*NCAND + col] = 2.f*A1[3] - cn; \
    } }
  EPI(0, acc00, acc10)
  EPI(1, acc01, acc11)
  EPI(2, acc02, acc12)
  EPI(3, acc03, acc13)
#undef EPI

  // sample column: cand c0 (always < NCAND), held by n16==0 lanes in NT=0 accs
  if (n16 == 0) {
    float cn0 = candn[c0];
#pragma unroll
    for (int i = 0; i < 4; ++i) {
      samp[(size_t)(rb0+i)*SAMPP + blockIdx.x] = 2.f*acc00[i] - cn0;
      samp[(size_t)(rb1+i)*SAMPP + blockIdx.x] = 2.f*acc10[i] - cn0;
    }
  }
}

// ---------------- select stage 1 (dense sample buffer) ----------------
__global__ void __launch_bounds__(256) k_sample(
    const float* __restrict__ samp, float* __restrict__ gthr, unsigned* __restrict__ gcnt)
{
  __shared__ float sv[NSAMP];
  __shared__ unsigned hist[256];
  __shared__ float wmin[4], wmax[4];
  __shared__ float s_lo, s_inv, s_w;
  const int tid = threadIdx.x, row = blockIdx.x;
  const float* S = samp + (size_t)row*SAMPP;
  float lmax = -__builtin_inff(), lmin = __builtin_inff();
  for (int i = tid; i < NSAMP; i += 256) {
    float v = S[i];
    sv[i] = v;
    lmax = fmaxf(lmax, v); lmin = fminf(lmin, v);
  }
  if (tid < 256) hist[tid] = 0;
  for (int o = 32; o; o >>= 1) {
    lmax = fmaxf(lmax, __shfl_xor(lmax, o));
    lmin = fminf(lmin, __shfl_xor(lmin, o));
  }
  if ((tid & 63) == 0) { wmax[tid>>6] = lmax; wmin[tid>>6] = lmin; }
  __syncthreads();
  if (tid == 0) {
    float hi = wmax[0], lo = wmin[0];
    for (int w = 1; w < 4; ++w) { hi = fmaxf(hi, wmax[w]); lo = fminf(lo, wmin[w]); }
    float rng = hi - lo;
    s_lo = lo;
    s_inv = (rng > 0.f) ? (256.f/rng) : 0.f;
    s_w   = (rng > 0.f) ? (rng/256.f) : 0.f;
  }
  __syncthreads();
  const float lo = s_lo, inv = s_inv;
  for (int i = tid; i < NSAMP; i += 256) {
    int b = min(max((int)((sv[i]-lo)*inv), 0), 255);
    atomicAdd(&hist[b], 1u);
  }
  __syncthreads();
  if (tid == 0) {
    unsigned cum = 0; int b = 255;
    for (; b >= 1; --b) { if (cum + hist[b] >= 24u) break; cum += hist[b]; }
    gthr[row] = lo + (float)b * s_w;
    gcnt[row] = 0u;
  }
}

// ---------------- select stage 2 ----------------
__global__ void __launch_bounds__(256) k_emit(
    const float* __restrict__ sims, const float* __restrict__ gthr,
    unsigned* __restrict__ gcnt, float* __restrict__ ev, int* __restrict__ ei)
{
  __shared__ float lv[BCAP];
  __shared__ int   li[BCAP];
  __shared__ unsigned lcnt, lbase;
  const int tid = threadIdx.x;
  const int row = blockIdx.y;
  const int base = blockIdx.x * 12500;
  const float thr = gthr[row];
  const float* S = sims + (size_t)row*NCAND + base;
  if (tid == 0) lcnt = 0;
  __syncthreads();
  for (int i = tid; i < 3125; i += 256) {
    float4 v = *(const float4*)&S[i*4];
    if (v.x >= thr) { unsigned p = atomicAdd(&lcnt, 1u); if (p < BCAP) { lv[p] = v.x; li[p] = base + i*4 + 0; } }
    if (v.y >= thr) { unsigned p = atomicAdd(&lcnt, 1u); if (p < BCAP) { lv[p] = v.y; li[p] = base + i*4 + 1; } }
    if (v.z >= thr) { unsigned p = atomicAdd(&lcnt, 1u); if (p < BCAP) { lv[p] = v.z; li[p] = base + i*4 + 2; } }
    if (v.w >= thr) { unsigned p = atomicAdd(&lcnt, 1u); if (p < BCAP) { lv[p] = v.w; li[p] = base + i*4 + 3; } }
  }
  __syncthreads();
  const int n = (int)min(lcnt, (unsigned)BCAP);
  if (tid == 0) lbase = atomicAdd(&gcnt[row], (unsigned)n);
  __syncthreads();
  const unsigned gb = lbase;
  float* EV = ev + (size_t)row*EMCAP;
  int*   EI = ei + (size_t)row*EMCAP;
  for (int i = tid; i < n; i += 256) {
    unsigned p = gb + i;
    if (p < EMCAP) { EV[p] = lv[i]; EI[p] = li[i]; }
  }
}

// ---------------- select stage 3 ----------------
__global__ void __launch_bounds__(256) k_final(
    const float* __restrict__ ev, const int* __restrict__ ei,
    const unsigned* __restrict__ gcnt, const float* __restrict__ cand_y,
    float* __restrict__ probs, int* __restrict__ tidxg, float* __restrict__ ygath,
    int r0)
{
  __shared__ float sv[EMCAP];
  __shared__ unsigned hist[1024];
  __shared__ float tv[512]; __shared__ int ti[512];
  __shared__ float selv[96]; __shared__ int seli[96];
  __shared__ unsigned cnts[2];
  __shared__ float wv[4]; __shared__ int wp[4];
  __shared__ float wmin[4], wmax[4];
  __shared__ float s_lo, s_inv;
  __shared__ int sb_s, above_s;
  __shared__ float smax_s, ssum_s;

  const int tid = threadIdx.x, row = blockIdx.x;
  const int n = (int)min(gcnt[row], (unsigned)EMCAP);
  const float* EV = ev + (size_t)row*EMCAP;
  const int*   EI = ei + (size_t)row*EMCAP;

  if (tid < 96) { selv[tid] = -1e30f; seli[tid] = 0; }
  for (int i = tid; i < 1024; i += 256) hist[i] = 0;
  if (tid < 2) cnts[tid] = 0;

  float lmax = -__builtin_inff(), lmin = __builtin_inff();
  for (int i = tid; i < n; i += 256) {
    float v = EV[i]; sv[i] = v;
    lmax = fmaxf(lmax, v); lmin = fminf(lmin, v);
  }
  for (int o = 32; o; o >>= 1) {
    lmax = fmaxf(lmax, __shfl_xor(lmax, o));
    lmin = fminf(lmin, __shfl_xor(lmin, o));
  }
  if ((tid & 63) == 0) { wmax[tid>>6] = lmax; wmin[tid>>6] = lmin; }
  __syncthreads();
  if (tid == 0) {
    float hi = wmax[0], lo = wmin[0];
    for (int w2 = 1; w2 < 4; ++w2) { hi = fmaxf(hi, wmax[w2]); lo = fminf(lo, wmin[w2]); }
    float rng = hi - lo;
    s_lo = lo; s_inv = (rng > 0.f) ? (1024.f/rng) : 0.f;
  }
  __syncthreads();
  const float lo = s_lo, inv = s_inv;

  for (int i = tid; i < n; i += 256) {
    int b = min(max((int)((sv[i]-lo)*inv), 0), 1023);
    atomicAdd(&hist[b], 1u);
  }
  __syncthreads();
  if (tid == 0) {
    unsigned cum = 0; int b = 1023;
    for (; b >= 1; --b) { if (cum + hist[b] >= 96u) break; cum += hist[b]; }
    sb_s = b; above_s = (int)cum;
  }
  __syncthreads();
  const int sb = sb_s, above = above_s;

  for (int i = tid; i < n; i += 256) {
    float v = sv[i];
    int b = min(max((int)((v-lo)*inv), 0), 1023);
    if (b > sb) {
      unsigned p = atomicAdd(&cnts[0], 1u);
      if (p < 96u) { selv[p] = v; seli[p] = EI[i]; }
    } else if (b == sb) {
      unsigned p = atomicAdd(&cnts[1], 1u);
      if (p < 512u) { tv[p] = v; ti[p] = EI[i]; }
    }
  }
  __syncthreads();
  const int need = 96 - above;
  const int tcnt = (int)min(cnts[1], 512u);
  for (int rd = 0; rd < need; ++rd) {
    float best = -__builtin_inff(); int bp = -1;
    for (int t = tid; t < tcnt; t += 256) {
      float v = tv[t];
      if (v > best) { best = v; bp = t; }
    }
    for (int o = 32; o; o >>= 1) {
      float ob = __shfl_xor(best, o); int obp = __shfl_xor(bp, o);
      if (ob > best) { best = ob; bp = obp; }
    }
    if ((tid & 63) == 0) { wv[tid>>6] = best; wp[tid>>6] = bp; }
    __syncthreads();
    if (tid == 0) {
      float bb = wv[0]; int pp = wp[0];
      for (int w2 = 1; w2 < 4; ++w2) if (wv[w2] > bb) { bb = wv[w2]; pp = wp[w2]; }
      if (pp >= 0) { selv[above + rd] = bb; seli[above + rd] = ti[pp]; tv[pp] = -__builtin_inff(); }
    }
    __syncthreads();
  }

  if (tid == 0) {
    float m = selv[0];
    for (int i = 1; i < 96; ++i) m = fmaxf(m, selv[i]);
    smax_s = m;
  }
  __syncthreads();
  if (tid < 96) selv[tid] = expf(selv[tid] - smax_s);
  __syncthreads();
  if (tid == 0) {
    float s = 0.f;
    for (int i = 0; i < 96; ++i) s += selv[i];
    ssum_s = s;
  }
  __syncthreads();
  if (tid < 96) {
    int gr = r0 + row;
    int gi = seli[tid];
    probs[(size_t)gr*96 + tid] = selv[tid]/ssum_s;
    tidxg[(size_t)gr*96 + tid] = gi;
    ygath[(size_t)gr*96 + tid] = cand_y[gi];
  }
}

// ---------------- context accumulation ----------------
__global__ void __launch_bounds__(128) k_ctx(
    const float* __restrict__ probs, const float* __restrict__ ygath,
    const float* __restrict__ t2, const float* __restrict__ x2b,
    const float* __restrict__ w_le, const float* __restrict__ b_le,
    float* __restrict__ xfinal)
{
  int bb = blockIdx.x;
  int d = threadIdx.x;
  float wle = w_le[d], ble = b_le[d];
  float acc = 0.f;
  for (int c = 0; c < 96; ++c) {
    float p = probs[(size_t)bb*96 + c];
    float y = ygath[(size_t)bb*96 + c];
    acc += p*(y*wle + ble + t2[(size_t)(bb*96 + c)*128 + d]);
  }
  xfinal[(size_t)bb*128 + d] = x2b[(size_t)bb*128 + d] + acc;
}

// ---------------- head ----------------
__global__ void __launch_bounds__(256) k_head(
    const float* __restrict__ x, const float* __restrict__ g, const float* __restrict__ b,
    const float* __restrict__ Wh, const float* __restrict__ bh,
    float* __restrict__ out, int M)
{
  const int lane = threadIdx.x & 63, w = threadIdx.x >> 6;
  int rb = blockIdx.x*32 + w*8;
  for (int it = 0; it < 8; ++it) {
    int r = rb + it;
    if (r >= M) return;
    float a = x[(size_t)r*128 + lane];
    float c = x[(size_t)r*128 + 64 + lane];
    float s = a + c;
    for (int o = 32; o; o >>= 1) s += __shfl_xor(s, o);
    float mu = s*(1.f/128.f);
    float da = a - mu, dc = c - mu;
    float v = da*da + dc*dc;
    for (int o = 32; o; o >>= 1) v += __shfl_xor(v, o);
    float rs = rsqrtf(v*(1.f/128.f) + 1e-5f);
    float l0 = fmaxf(da*rs*g[lane]    + b[lane],    0.f);
    float l1 = fmaxf(dc*rs*g[lane+64] + b[lane+64], 0.f);
    float p0 = l0*Wh[lane]     + l1*Wh[64+lane];
    float p1 = l0*Wh[128+lane] + l1*Wh[192+lane];
    for (int o = 32; o; o >>= 1) { p0 += __shfl_xor(p0, o); p1 += __shfl_xor(p1, o); }
    if (lane == 0) { out[r*2 + 0] = p0 + bh[0]; out[r*2 + 1] = p1 + bh[1]; }
  }
}

// ---------------- launcher ----------------
extern "C" void kernel_launch(void* const* d_in, const int* in_sizes, int n_in,
                              void* d_out, int out_size, void* d_ws, size_t ws_size,
                              hipStream_t stream) {
  const float* x_num   = (const float*)d_in[0];
  const float* cand_x  = (const float*)d_in[1];
  const float* cand_y  = (const float*)d_in[2];
  const float* W_in    = (const float*)d_in[3];
  const float* b_in    = (const float*)d_in[4];
  const float* enc_W1  = (const float*)d_in[5];
  const float* enc_b1  = (const float*)d_in[6];
  const float* enc_W2  = (const float*)d_in[7];
  const float* enc_b2  = (const float*)d_in[8];
  const float* mix_g   = (const float*)d_in[9];
  const float* mix_b   = (const float*)d_in[10];
  const float* W_k     = (const float*)d_in[11];
  const float* b_k     = (const float*)d_in[12];
  const float* w_le    = (const float*)d_in[13];
  const float* b_le    = (const float*)d_in[14];
  const float* W_t1    = (const float*)d_in[15];
  const float* b_t1    = (const float*)d_in[16];
  const float* W_t2    = (const float*)d_in[17];
  const float* pred_g  = (const float*)d_in[18];
  const float* pred_b  = (const float*)d_in[19];
  const float* pred_W1 = (const float*)d_in[20];
  const float* pred_b1 = (const float*)d_in[21];
  const float* pred_W2 = (const float*)d_in[22];
  const float* pred_b2 = (const float*)d_in[23];
  const float* head_g  = (const float*)d_in[24];
  const float* head_b  = (const float*)d_in[25];
  const float* W_head  = (const float*)d_in[26];
  const float* b_head  = (const float*)d_in[27];

  float* ws  = (float*)d_ws;
  float* out = (float*)d_out;

  float*          wt     = ws;
  unsigned short* Wh     = (unsigned short*)ws;
  unsigned short* Wl     = Wh + 155648;
  unsigned short* ckh    = (unsigned short*)(ws + OFF_CKH);
  unsigned short* ckl    = (unsigned short*)(ws + OFF_CKL);
  float*          candn  = ws + OFF_CANDN;
  float*          kb     = ws + OFF_KB;
  float*          x2b    = ws + OFF_X2B;
  float*          lnb    = ws + OFF_LNB;
  float*          hb     = ws + OFF_HB;
  float*          xpred  = ws + OFF_XPRED;
  float*          xfin   = ws + OFF_XFIN;
  unsigned short* kbAh   = (unsigned short*)(ws + OFF_KBA);
  unsigned short* kbAl   = kbAh + 131072;
  float*          probs  = ws + OFF_PROBS;
  int*            tidxg  = (int*)(ws + OFF_TIDX);
  float*          ygath  = ws + OFF_YG;
  float*          simsbuf = ws + OFF_SX;
  float*          t2buf  = ws + OFF_SX;
  float*          ev     = ws + OFF_EV;
  int*            ei     = (int*)(ws + OFF_EI);
  unsigned*       gcnt   = (unsigned*)(ws + OFF_GCNT);
  float*          gthr   = ws + OFF_GTHR;
  float*          samp   = ws + OFF_SAMP;

  // 1) weight prep
  k_cvt_w<<<96, 256, 0, stream>>>(W_in, enc_W1, enc_W2, W_k, W_t1, W_t2, Wh, Wl);
  k_transpose<<<64, 256, 0, stream>>>(pred_W1, pred_W2, wt);
  k_pad_ck<<<16, 256, 0, stream>>>(ckh, ckl);

  // 2) batch encoder (fused) -> x2b, kb; then kb -> A-frags
  k_enc_fused<true><<<BATCH/64, 256, 0, stream>>>(
      x_num, Wh, Wl, b_in, enc_b1, enc_b2, mix_g, mix_b, b_k,
      nullptr, nullptr, nullptr, x2b, kb, BATCH);
  k_cvt_kbA<<<512, 256, 0, stream>>>(kb, kbAh, kbAl);

  // 3) candidate encoder (fused) -> ckh/ckl, candn
  k_enc_fused<false><<<(NCAND+63)/64, 256, 0, stream>>>(
      cand_x, Wh, Wl, b_in, enc_b1, enc_b2, mix_g, mix_b, b_k,
      ckh, ckl, candn, nullptr, nullptr, NCAND);

  // 4) sims (MFMA, fused sample) + exact top-96, 8 row chunks of 128
  for (int ch = 0; ch < 8; ++ch) {
    k_sims_mfma<<<NCPAD/64, 256, 0, stream>>>(kbAh, kbAl, ckh, ckl, candn, simsbuf, samp, ch);
    k_sample<<<RCH, 256, 0, stream>>>(samp, gthr, gcnt);
    k_emit<<<dim3(8, RCH), 256, 0, stream>>>(simsbuf, gthr, gcnt, ev, ei);
    k_final<<<RCH, 256, 0, stream>>>(ev, ei, gcnt, cand_y, probs, tidxg, ygath, ch*RCH);
  }

  // 5) t-net (fused MFMA) + context
  k_tnet<<<NPAIR/64, 256, 0, stream>>>(kb, ckh, ckl, tidxg, Wh, Wl, b_t1, t2buf);
  k_ctx<<<BATCH, 128, 0, stream>>>(probs, ygath, t2buf, x2b, w_le, b_le, xfin);

  // 6) predictor block + head
  k_ln<<<(BATCH+31)/32, 256, 0, stream>>>(xfin, pred_g, pred_b, lnb, BATCH);
  k_gemm<256,true ,false><<<16, 256, 0, stream>>>(lnb, wt+WT_P1, pred_b1, nullptr, hb,    BATCH, 128);
  k_gemm<128,false,true ><<<16, 256, 0, stream>>>(hb,  wt+WT_P2, pred_b2, xfin,    xpred, BATCH, 256);
  k_head<<<(BATCH+31)/32, 256, 0, stream>>>(xpred, head_g, head_b, W_head, b_head, out, BATCH);
}

// Round 10
// 1275.137 us; speedup vs baseline: 1.2287x; 1.2287x over previous
//
#include <hip/hip_runtime.h>
#include <math.h>

// ---------------- problem sizes ----------------
#define BATCH   1024
#define NCAND   100000
#define NCPAD   100032
#define DM      128
#define DB      256
#define NNUM    64
#define CTXS    96
#define NPAIR   (BATCH*CTXS)   // 98304
#define RCH     128
#define EMCAP   8192
#define BCAP    1024
#define NSAMP   1563
#define SAMPP   1600

// ---------------- workspace offsets ----------------
// Wh/Wl: bf16 hi/lo weights in B-FRAGMENT SLICE-MAJOR order:
//   offset(m; ks, nt, lane, j) = base + ((ks*NT + nt)*64 + lane)*8 + j
//   element = W[nt*16 + (lane&15)][ks*32 + (lane>>4)*8 + j]
#define WB_IN       0u
#define WB_E1       8192u
#define WB_E2       40960u
#define WB_K        73728u
#define WB_T1       90112u
#define WB_T2       122880u
#define WT_P1       155648u
#define WT_P2       188416u
#define OFF_CKH     221184u      // 100032*128 bf16 hi
#define OFF_CKL     6623232u     // 100032*128 bf16 lo
#define OFF_CANDN   13025280u
#define OFF_KB      13125280u
#define OFF_X2B     13387424u
#define OFF_LNB     13518496u
#define OFF_HB      13649568u
#define OFF_XPRED   13911712u
#define OFF_XFIN    14042784u
#define OFF_KBA     14173856u
#define OFF_PROBS   15743648u
#define OFF_TIDX    15841952u
#define OFF_YG      15940256u
#define OFF_SX      16038560u
#define OFF_EV      28838560u
#define OFF_EI      29887136u
#define OFF_GCNT    30935712u
#define OFF_GTHR    30935840u
#define OFF_SAMP    30935968u

typedef __attribute__((ext_vector_type(8))) short bf16x8;
typedef __attribute__((ext_vector_type(4))) float f32x4;
#define MFMA16(A,B,C) C = __builtin_amdgcn_mfma_f32_16x16x32_bf16(A, B, C, 0, 0, 0)

__device__ __forceinline__ unsigned short f2bf(float x) {
  unsigned u = __float_as_uint(x);
  unsigned r = (u + 0x7FFFu + ((u >> 16) & 1u)) >> 16;
  return (unsigned short)r;
}
__device__ __forceinline__ float bf2f(unsigned short h) {
  return __uint_as_float(((unsigned)h) << 16);
}

// ---------------- prep ----------------
__global__ void __launch_bounds__(256) k_transpose(
    const float* __restrict__ w0, const float* __restrict__ w1,
    float* __restrict__ dst)
{
  const float* src[2] = {w0,w1};
  const int nn[2]  = {256,128};
  const int kkv[2] = {128,256};
  const int off[2] = {155648,188416};
  int stride = gridDim.x*blockDim.x;
  int t0 = blockIdx.x*blockDim.x + threadIdx.x;
#pragma unroll
  for (int m = 0; m < 2; ++m) {
    int total = nn[m]*kkv[m];
    for (int i = t0; i < total; i += stride) {
      int k = i / nn[m];
      int n = i - k*nn[m];
      dst[off[m] + i] = src[m][n*kkv[m] + k];
    }
  }
}

// weights -> bf16 hi/lo in B-frag slice-major order
__global__ void __launch_bounds__(256) k_cvt_w(
    const float* __restrict__ w_in, const float* __restrict__ e1,
    const float* __restrict__ e2, const float* __restrict__ wk,
    const float* __restrict__ t1, const float* __restrict__ t2,
    unsigned short* __restrict__ Wh, unsigned short* __restrict__ Wl)
{
  const float* src[6] = {w_in, e1, e2, wk, t1, t2};
  const int NN[6] = {128, 256, 128, 128, 256, 128};
  const int KK[6] = { 64, 128, 256, 128, 128, 256};
  const int off[6] = {WB_IN, WB_E1, WB_E2, WB_K, WB_T1, WB_T2};
  int stride = gridDim.x*blockDim.x;
  int t0 = blockIdx.x*blockDim.x + threadIdx.x;
#pragma unroll
  for (int m = 0; m < 6; ++m) {
    const int NT = NN[m] >> 4;
    const int K = KK[m];
    const int total = NN[m]*K;
    for (int i = t0; i < total; i += stride) {
      int j = i & 7;
      int lane = (i >> 3) & 63;
      int rem = i >> 9;              // ks*NT + nt
      int nt = rem % NT, ks = rem / NT;
      int row = nt*16 + (lane & 15);
      int col = ks*32 + (lane >> 4)*8 + j;
      float x = src[m][row*K + col];
      unsigned short h = f2bf(x);
      Wh[off[m]+i] = h;
      Wl[off[m]+i] = f2bf(x - bf2f(h));
    }
  }
}

__global__ void __launch_bounds__(256) k_pad_ck(
    unsigned short* __restrict__ ckh, unsigned short* __restrict__ ckl)
{
  int i = blockIdx.x*256 + threadIdx.x;
  if (i < 4096) {
    ckh[(size_t)NCAND*128 + i] = 0;
    ckl[(size_t)NCAND*128 + i] = 0;
  }
}

__global__ void __launch_bounds__(256) k_cvt_kbA(
    const float* __restrict__ kb,
    unsigned short* __restrict__ kbAh, unsigned short* __restrict__ kbAl)
{
  int i = blockIdx.x*256 + threadIdx.x;
  int j = i & 7, lane = (i >> 3) & 63, s = (i >> 9) & 3, mt = (i >> 11) & 7, ch = i >> 14;
  int row = ch*128 + mt*16 + (lane & 15);
  int k = s*32 + (lane >> 4)*8 + j;
  float x = kb[(size_t)row*128 + k];
  unsigned short h = f2bf(x);
  kbAh[i] = h;
  kbAl[i] = f2bf(x - bf2f(h));
}

// ---------------- FUSED ENCODER v5: 128 rows/block, LDS-staged weights ----------------
// LDS: sAct 64KB = 4 x 16KB wave-private (x hi/lo -> H -> ln hi/lo);
//      sWt 64KB = 2 x 32KB double-buffered weight k-slices (block-shared).
// Each wave: 2 mt (32 rows). Weight slices staged cooperatively per ks.
template<bool BATCHOUT>
__global__ void __launch_bounds__(256, 2) k_enc_fused(
    const float* __restrict__ xnum,
    const unsigned short* __restrict__ Wh, const unsigned short* __restrict__ Wl,
    const float* __restrict__ b_in, const float* __restrict__ b1,
    const float* __restrict__ b2, const float* __restrict__ mix_g,
    const float* __restrict__ mix_b, const float* __restrict__ b_k,
    unsigned short* __restrict__ ckh, unsigned short* __restrict__ ckl,
    float* __restrict__ candn,
    float* __restrict__ x2out, float* __restrict__ kout,
    int M)
{
  __shared__ __align__(16) unsigned short sAct[32768];  // 64KB
  __shared__ __align__(16) unsigned short sWt[32768];   // 64KB
  const int tid = threadIdx.x;
  const int wv = tid >> 6, lane = tid & 63;
  const int q = lane >> 4, n16 = lane & 15;
  const int r0 = blockIdx.x * 128;
  unsigned short* wbuf = sAct + wv*8192;   // 16KB wave-private

  // cooperative weight slice staging: slice ks of matrix at 'base' (NT tiles)
  auto stageW = [&](unsigned base, int NT, int ks, int slot) {
    const int n = NT*64;
    const unsigned short* sh = Wh + base + (size_t)ks*n*8;
    const unsigned short* sl = Wl + base + (size_t)ks*n*8;
    unsigned short* dh = sWt + slot*16384;
    unsigned short* dl = dh + 8192;
    for (int i = tid; i < n; i += 256) {
      *(bf16x8*)(dh + i*8) = *(const bf16x8*)(sh + i*8);
      *(bf16x8*)(dl + i*8) = *(const bf16x8*)(sl + i*8);
    }
  };

  // ---- phase 1 prep: A-frags of xnum from global (wave-private rows)
  bf16x8 xa_h[2][2], xa_l[2][2];   // [mt][ks]
#pragma unroll
  for (int mt = 0; mt < 2; ++mt) {
#pragma unroll
    for (int ks = 0; ks < 2; ++ks) {
      int row = r0 + wv*32 + mt*16 + n16;
      int k0 = ks*32 + q*8;
      float4 p0 = {0.f,0.f,0.f,0.f}, p1 = {0.f,0.f,0.f,0.f};
      if (row < M) {
        p0 = *(const float4*)&xnum[(size_t)row*64 + k0];
        p1 = *(const float4*)&xnum[(size_t)row*64 + k0 + 4];
      }
#define CV(di, val) { unsigned short hh = f2bf(val); xa_h[mt][ks][di] = (short)hh; xa_l[mt][ks][di] = (short)f2bf((val) - bf2f(hh)); }
      CV(0,p0.x) CV(1,p0.y) CV(2,p0.z) CV(3,p0.w) CV(4,p1.x) CV(5,p1.y) CV(6,p1.z) CV(7,p1.w)
#undef CV
    }
  }

  // ---- phase 1: x = xnum @ W_in^T + b_in   (NT=8, KS=2)
  f32x4 xc[2][8];
#pragma unroll
  for (int mt = 0; mt < 2; ++mt)
#pragma unroll
    for (int nt = 0; nt < 8; ++nt) {
      float b = b_in[nt*16 + n16];
      xc[mt][nt][0]=b; xc[mt][nt][1]=b; xc[mt][nt][2]=b; xc[mt][nt][3]=b;
    }
  stageW(WB_IN, 8, 0, 0);
  __syncthreads();
  for (int ks = 0; ks < 2; ++ks) {
    if (ks == 0) stageW(WB_IN, 8, 1, 1);
    const unsigned short* wh = sWt + (ks&1)*16384;
#pragma unroll
    for (int nt = 0; nt < 8; ++nt) {
      bf16x8 bh = *(const bf16x8*)(wh + (nt*64+lane)*8);
      bf16x8 bl = *(const bf16x8*)(wh + 8192 + (nt*64+lane)*8);
      MFMA16(xa_h[0][ks], bh, xc[0][nt]); MFMA16(xa_l[0][ks], bh, xc[0][nt]); MFMA16(xa_h[0][ks], bl, xc[0][nt]);
      MFMA16(xa_h[1][ks], bh, xc[1][nt]); MFMA16(xa_l[1][ks], bh, xc[1][nt]); MFMA16(xa_h[1][ks], bl, xc[1][nt]);
    }
    __syncthreads();
  }

  // ---- phase 2: x -> A-frags hi/lo in wave buf (hi [0..4095], lo [4096..8191])
#pragma unroll
  for (int mt = 0; mt < 2; ++mt)
#pragma unroll
    for (int nt = 0; nt < 8; ++nt) {
      int col = nt*16 + n16;
      int ks2 = col >> 5, q2 = (col >> 3) & 3, j2 = col & 7;
#pragma unroll
      for (int i = 0; i < 4; ++i) {
        int idx = (mt*4 + ks2)*512 + (q2*16 + q*4 + i)*8 + j2;
        float v = xc[mt][nt][i];
        unsigned short hh = f2bf(v);
        wbuf[idx] = hh;
        wbuf[4096 + idx] = f2bf(v - bf2f(hh));
      }
    }

  // ---- phase 3: H = relu(x @ E1^T + b1)   (NT=16, KS=4)
  f32x4 hc[2][16];
#pragma unroll
  for (int mt = 0; mt < 2; ++mt)
#pragma unroll
    for (int nt = 0; nt < 16; ++nt) { hc[mt][nt][0]=0.f; hc[mt][nt][1]=0.f; hc[mt][nt][2]=0.f; hc[mt][nt][3]=0.f; }
  stageW(WB_E1, 16, 0, 0);
  __syncthreads();
  for (int ks = 0; ks < 4; ++ks) {
    if (ks < 3) stageW(WB_E1, 16, ks+1, (ks+1)&1);
    const unsigned short* wh = sWt + (ks&1)*16384;
    bf16x8 ah0 = *(const bf16x8*)(wbuf + (0*4+ks)*512 + lane*8);
    bf16x8 al0 = *(const bf16x8*)(wbuf + 4096 + (0*4+ks)*512 + lane*8);
    bf16x8 ah1 = *(const bf16x8*)(wbuf + (1*4+ks)*512 + lane*8);
    bf16x8 al1 = *(const bf16x8*)(wbuf + 4096 + (1*4+ks)*512 + lane*8);
#pragma unroll
    for (int nt = 0; nt < 16; ++nt) {
      bf16x8 bh = *(const bf16x8*)(wh + (nt*64+lane)*8);
      bf16x8 bl = *(const bf16x8*)(wh + 8192 + (nt*64+lane)*8);
      MFMA16(ah0, bh, hc[0][nt]); MFMA16(al0, bh, hc[0][nt]); MFMA16(ah0, bl, hc[0][nt]);
      MFMA16(ah1, bh, hc[1][nt]); MFMA16(al1, bh, hc[1][nt]); MFMA16(ah1, bl, hc[1][nt]);
    }
    __syncthreads();
  }

  // ---- phase 3.5: init x2c = b2 + x(residual, from LDS) BEFORE H overwrites region
  f32x4 x2c[2][8];
#pragma unroll
  for (int mt = 0; mt < 2; ++mt)
#pragma unroll
    for (int nt = 0; nt < 8; ++nt) {
      float b = b2[nt*16 + n16];
      int col = nt*16 + n16;
      int ks2 = col >> 5, q2 = (col >> 3) & 3, j2 = col & 7;
#pragma unroll
      for (int i = 0; i < 4; ++i) {
        int idx = (mt*4 + ks2)*512 + (q2*16 + q*4 + i)*8 + j2;
        x2c[mt][nt][i] = b + bf2f(wbuf[idx]) + bf2f(wbuf[4096 + idx]);
      }
    }
  // H (single bf16) -> wave buf [0..8191] (overwrites x; wave-private, program order safe)
#pragma unroll
  for (int mt = 0; mt < 2; ++mt)
#pragma unroll
    for (int nt = 0; nt < 16; ++nt) {
      float b = b1[nt*16 + n16];
      int col = nt*16 + n16;
      int ks2 = col >> 5, q2 = (col >> 3) & 3, j2 = col & 7;
#pragma unroll
      for (int i = 0; i < 4; ++i) {
        float v = fmaxf(hc[mt][nt][i] + b, 0.f);
        wbuf[(mt*8 + ks2)*512 + (q2*16 + q*4 + i)*8 + j2] = f2bf(v);
      }
    }

  // ---- phase 4: x2 += H @ E2^T   (NT=8, KS=8)
  stageW(WB_E2, 8, 0, 0);
  __syncthreads();
  for (int ks = 0; ks < 8; ++ks) {
    if (ks < 7) stageW(WB_E2, 8, ks+1, (ks+1)&1);
    const unsigned short* wh = sWt + (ks&1)*16384;
    bf16x8 ha0 = *(const bf16x8*)(wbuf + (0*8+ks)*512 + lane*8);
    bf16x8 ha1 = *(const bf16x8*)(wbuf + (1*8+ks)*512 + lane*8);
#pragma unroll
    for (int nt = 0; nt < 8; ++nt) {
      bf16x8 bh = *(const bf16x8*)(wh + (nt*64+lane)*8);
      bf16x8 bl = *(const bf16x8*)(wh + 8192 + (nt*64+lane)*8);
      MFMA16(ha0, bh, x2c[0][nt]); MFMA16(ha0, bl, x2c[0][nt]);
      MFMA16(ha1, bh, x2c[1][nt]); MFMA16(ha1, bl, x2c[1][nt]);
    }
    __syncthreads();
  }
  if constexpr (BATCHOUT) {
#pragma unroll
    for (int mt = 0; mt < 2; ++mt)
#pragma unroll
      for (int nt = 0; nt < 8; ++nt) {
        int col = nt*16 + n16;
#pragma unroll
        for (int i = 0; i < 4; ++i) {
          int row = r0 + wv*32 + mt*16 + q*4 + i;
          if (row < M) x2out[(size_t)row*128 + col] = x2c[mt][nt][i];
        }
      }
  }

  // ---- phase 5: LayerNorm; ln hi/lo -> wave buf (overwrites H)
#pragma unroll
  for (int mt = 0; mt < 2; ++mt) {
#pragma unroll
    for (int i = 0; i < 4; ++i) {
      float s = 0.f;
#pragma unroll
      for (int nt = 0; nt < 8; ++nt) s += x2c[mt][nt][i];
      s += __shfl_xor(s, 1); s += __shfl_xor(s, 2); s += __shfl_xor(s, 4); s += __shfl_xor(s, 8);
      float mu = s * (1.f/128.f);
      float v = 0.f;
#pragma unroll
      for (int nt = 0; nt < 8; ++nt) { float d = x2c[mt][nt][i] - mu; v += d*d; }
      v += __shfl_xor(v, 1); v += __shfl_xor(v, 2); v += __shfl_xor(v, 4); v += __shfl_xor(v, 8);
      float rs = rsqrtf(v*(1.f/128.f) + 1e-5f);
#pragma unroll
      for (int nt = 0; nt < 8; ++nt) {
        float lv = (x2c[mt][nt][i] - mu)*rs*mix_g[nt*16 + n16] + mix_b[nt*16 + n16];
        int col = nt*16 + n16;
        int ks2 = col >> 5, q2 = (col >> 3) & 3, j2 = col & 7;
        int idx = (mt*4 + ks2)*512 + (q2*16 + q*4 + i)*8 + j2;
        unsigned short hh = f2bf(lv);
        wbuf[idx] = hh;
        wbuf[4096 + idx] = f2bf(lv - bf2f(hh));
      }
    }
  }

  // ---- phase 6: k = ln @ W_k^T + b_k   (NT=8, KS=4)
  f32x4 kc[2][8];
#pragma unroll
  for (int mt = 0; mt < 2; ++mt)
#pragma unroll
    for (int nt = 0; nt < 8; ++nt) {
      float b = b_k[nt*16 + n16];
      kc[mt][nt][0]=b; kc[mt][nt][1]=b; kc[mt][nt][2]=b; kc[mt][nt][3]=b;
    }
  stageW(WB_K, 8, 0, 0);
  __syncthreads();
  for (int ks = 0; ks < 4; ++ks) {
    if (ks < 3) stageW(WB_K, 8, ks+1, (ks+1)&1);
    const unsigned short* wh = sWt + (ks&1)*16384;
    bf16x8 ah0 = *(const bf16x8*)(wbuf + (0*4+ks)*512 + lane*8);
    bf16x8 al0 = *(const bf16x8*)(wbuf + 4096 + (0*4+ks)*512 + lane*8);
    bf16x8 ah1 = *(const bf16x8*)(wbuf + (1*4+ks)*512 + lane*8);
    bf16x8 al1 = *(const bf16x8*)(wbuf + 4096 + (1*4+ks)*512 + lane*8);
#pragma unroll
    for (int nt = 0; nt < 8; ++nt) {
      bf16x8 bh = *(const bf16x8*)(wh + (nt*64+lane)*8);
      bf16x8 bl = *(const bf16x8*)(wh + 8192 + (nt*64+lane)*8);
      MFMA16(ah0, bh, kc[0][nt]); MFMA16(al0, bh, kc[0][nt]); MFMA16(ah0, bl, kc[0][nt]);
      MFMA16(ah1, bh, kc[1][nt]); MFMA16(al1, bh, kc[1][nt]); MFMA16(ah1, bl, kc[1][nt]);
    }
    __syncthreads();
  }

  // ---- phase 7: outputs
#pragma unroll
  for (int mt = 0; mt < 2; ++mt) {
#pragma unroll
    for (int i = 0; i < 4; ++i) {
      int row = r0 + wv*32 + mt*16 + q*4 + i;
      if constexpr (!BATCHOUT) {
        float s2 = 0.f;
#pragma unroll
        for (int nt = 0; nt < 8; ++nt) { float kv = kc[mt][nt][i]; s2 += kv*kv; }
        s2 += __shfl_xor(s2, 1); s2 += __shfl_xor(s2, 2); s2 += __shfl_xor(s2, 4); s2 += __shfl_xor(s2, 8);
        if (n16 == 0 && row < M) candn[row] = s2;
      }
#pragma unroll
      for (int nt = 0; nt < 8; ++nt) {
        int col = nt*16 + n16;
        float kv = kc[mt][nt][i];
        if (row < M) {
          if constexpr (BATCHOUT) {
            kout[(size_t)row*128 + col] = kv;
          } else {
            unsigned short hh = f2bf(kv);
            ckh[(size_t)row*128 + col] = hh;
            ckl[(size_t)row*128 + col] = f2bf(kv - bf2f(hh));
          }
        }
      }
    }
  }
}

// ---------------- FUSED T-NET: barrier-free, 64 pairs/block (swizzled weights) ----------------
__global__ void __launch_bounds__(256) k_tnet(
    const float* __restrict__ kb,
    const unsigned short* __restrict__ ckh, const unsigned short* __restrict__ ckl,
    const int* __restrict__ tidxg,
    const unsigned short* __restrict__ Wh, const unsigned short* __restrict__ Wl,
    const float* __restrict__ b_t1, float* __restrict__ t2out)
{
  __shared__ __align__(16) unsigned short sBuf[16384];
  const int tid = threadIdx.x;
  const int wv = tid >> 6, lane = tid & 63;
  const int q = lane >> 4, n16 = lane & 15;
  const int p0 = blockIdx.x * 64;
  unsigned short* wbuf = sBuf + wv*4096;

#pragma unroll
  for (int ks = 0; ks < 4; ++ks) {
    int m = lane & 15, qq = lane >> 4;
    int gp = p0 + wv*16 + m;
    int d  = ks*32 + qq*8;
    int idx = tidxg[gp];
    int bb  = gp / 96;
    bf16x8 h8 = *(const bf16x8*)(ckh + (size_t)idx*128 + d);
    bf16x8 l8 = *(const bf16x8*)(ckl + (size_t)idx*128 + d);
    float4 k0 = *(const float4*)&kb[(size_t)bb*128 + d];
    float4 k1 = *(const float4*)&kb[(size_t)bb*128 + d + 4];
    bf16x8 df;
    df[0] = (short)f2bf(k0.x - (bf2f(h8[0]) + bf2f(l8[0])));
    df[1] = (short)f2bf(k0.y - (bf2f(h8[1]) + bf2f(l8[1])));
    df[2] = (short)f2bf(k0.z - (bf2f(h8[2]) + bf2f(l8[2])));
    df[3] = (short)f2bf(k0.w - (bf2f(h8[3]) + bf2f(l8[3])));
    df[4] = (short)f2bf(k1.x - (bf2f(h8[4]) + bf2f(l8[4])));
    df[5] = (short)f2bf(k1.y - (bf2f(h8[5]) + bf2f(l8[5])));
    df[6] = (short)f2bf(k1.z - (bf2f(h8[6]) + bf2f(l8[6])));
    df[7] = (short)f2bf(k1.w - (bf2f(h8[7]) + bf2f(l8[7])));
    *(bf16x8*)(wbuf + ks*512 + lane*8) = df;
  }

  // T1: NT=16, KS=4
  f32x4 hc[16];
#pragma unroll
  for (int nt = 0; nt < 16; ++nt) { hc[nt][0]=0.f; hc[nt][1]=0.f; hc[nt][2]=0.f; hc[nt][3]=0.f; }
#pragma unroll
  for (int ks = 0; ks < 4; ++ks) {
    bf16x8 ad = *(const bf16x8*)(wbuf + ks*512 + lane*8);
#pragma unroll
    for (int nt = 0; nt < 16; ++nt) {
      size_t wo = WB_T1 + (size_t)((ks*16 + nt)*64 + lane)*8;
      bf16x8 bh = *(const bf16x8*)(Wh + wo);
      bf16x8 bl = *(const bf16x8*)(Wl + wo);
      MFMA16(ad, bh, hc[nt]); MFMA16(ad, bl, hc[nt]);
    }
  }
#pragma unroll
  for (int nt = 0; nt < 16; ++nt) {
    float b = b_t1[nt*16 + n16];
    int col = nt*16 + n16;
    int ks2 = col >> 5, q2 = (col >> 3) & 3, j2 = col & 7;
#pragma unroll
    for (int i = 0; i < 4; ++i) {
      float v = fmaxf(hc[nt][i] + b, 0.f);
      wbuf[ks2*512 + (q2*16 + q*4 + i)*8 + j2] = f2bf(v);
    }
  }

  // T2: NT=8, KS=8
  f32x4 tc[8];
#pragma unroll
  for (int nt = 0; nt < 8; ++nt) { tc[nt][0]=0.f; tc[nt][1]=0.f; tc[nt][2]=0.f; tc[nt][3]=0.f; }
#pragma unroll
  for (int ks = 0; ks < 8; ++ks) {
    bf16x8 ha = *(const bf16x8*)(wbuf + ks*512 + lane*8);
#pragma unroll
    for (int nt = 0; nt < 8; ++nt) {
      size_t wo = WB_T2 + (size_t)((ks*8 + nt)*64 + lane)*8;
      bf16x8 bh = *(const bf16x8*)(Wh + wo);
      bf16x8 bl = *(const bf16x8*)(Wl + wo);
      MFMA16(ha, bh, tc[nt]); MFMA16(ha, bl, tc[nt]);
    }
  }
#pragma unroll
  for (int nt = 0; nt < 8; ++nt) {
    int col = nt*16 + n16;
#pragma unroll
    for (int i = 0; i < 4; ++i) {
      int pr = p0 + wv*16 + q*4 + i;
      t2out[(size_t)pr*128 + col] = tc[nt][i];
    }
  }
}

// ---------------- generic fp32 GEMM (predictor) ----------------
template<int N, bool RELU, bool RESID>
__global__ void __launch_bounds__(256) k_gemm(
    const float* __restrict__ A, const float* __restrict__ WT,
    const float* __restrict__ bias, const float* __restrict__ resid,
    float* __restrict__ C, int M, int K)
{
  constexpr int G = N/64;
  __shared__ __align__(16) float sA[64*33];
  __shared__ __align__(16) float sW[32*N];
  const int tid = threadIdx.x;
  const int r0 = blockIdx.x*64;
  const int tr = tid >> 4, tc = tid & 15;
  float acc[4][G*4];
#pragma unroll
  for (int i = 0; i < 4; ++i)
#pragma unroll
    for (int j = 0; j < G*4; ++j) acc[i][j] = 0.f;

  for (int kc = 0; kc < K; kc += 32) {
    for (int i = tid; i < 64*32; i += 256) {
      int r = i >> 5, kk = i & 31;
      int gr = r0 + r;
      sA[r*33 + kk] = (gr < M) ? A[(size_t)gr*K + kc + kk] : 0.f;
    }
    for (int i = tid; i < 32*N; i += 256) sW[i] = WT[(size_t)kc*N + i];
    __syncthreads();
    for (int kk = 0; kk < 32; ++kk) {
      float a0 = sA[(tr*4+0)*33+kk];
      float a1 = sA[(tr*4+1)*33+kk];
      float a2 = sA[(tr*4+2)*33+kk];
      float a3 = sA[(tr*4+3)*33+kk];
#pragma unroll
      for (int g = 0; g < G; ++g) {
        float4 w = *(const float4*)&sW[kk*N + g*64 + tc*4];
        acc[0][g*4+0] += a0*w.x; acc[0][g*4+1] += a0*w.y; acc[0][g*4+2] += a0*w.z; acc[0][g*4+3] += a0*w.w;
        acc[1][g*4+0] += a1*w.x; acc[1][g*4+1] += a1*w.y; acc[1][g*4+2] += a1*w.z; acc[1][g*4+3] += a1*w.w;
        acc[2][g*4+0] += a2*w.x; acc[2][g*4+1] += a2*w.y; acc[2][g*4+2] += a2*w.z; acc[2][g*4+3] += a2*w.w;
        acc[3][g*4+0] += a3*w.x; acc[3][g*4+1] += a3*w.y; acc[3][g*4+2] += a3*w.z; acc[3][g*4+3] += a3*w.w;
      }
    }
    __syncthreads();
  }

#pragma unroll
  for (int i = 0; i < 4; ++i) {
    int r = r0 + tr*4 + i;
    if (r < M) {
#pragma unroll
      for (int g = 0; g < G; ++g) {
        int col = g*64 + tc*4;
        float v0 = acc[i][g*4+0], v1 = acc[i][g*4+1], v2 = acc[i][g*4+2], v3 = acc[i][g*4+3];
        if (bias) { v0 += bias[col+0]; v1 += bias[col+1]; v2 += bias[col+2]; v3 += bias[col+3]; }
        if constexpr (RELU) { v0 = fmaxf(v0,0.f); v1 = fmaxf(v1,0.f); v2 = fmaxf(v2,0.f); v3 = fmaxf(v3,0.f); }
        if constexpr (RESID) {
          float4 rv = *(const float4*)&resid[(size_t)r*N + col];
          v0 += rv.x; v1 += rv.y; v2 += rv.z; v3 += rv.w;
        }
        float4 o4; o4.x = v0; o4.y = v1; o4.z = v2; o4.w = v3;
        *(float4*)&C[(size_t)r*N + col] = o4;
      }
    }
  }
}

// ---------------- LayerNorm (predictor prenorm) ----------------
__global__ void __launch_bounds__(256) k_ln(
    const float* __restrict__ x, const float* __restrict__ g, const float* __restrict__ b,
    float* __restrict__ o, int M)
{
  const int lane = threadIdx.x & 63, w = threadIdx.x >> 6;
  int rb = blockIdx.x*32 + w*8;
  for (int it = 0; it < 8; ++it) {
    int r = rb + it;
    if (r >= M) return;
    float a = x[(size_t)r*128 + lane];
    float c = x[(size_t)r*128 + 64 + lane];
    float s = a + c;
    for (int o2 = 32; o2; o2 >>= 1) s += __shfl_xor(s, o2);
    float mu = s * (1.f/128.f);
    float da = a - mu, dc = c - mu;
    float v = da*da + dc*dc;
    for (int o2 = 32; o2; o2 >>= 1) v += __shfl_xor(v, o2);
    float rs = rsqrtf(v*(1.f/128.f) + 1e-5f);
    o[(size_t)r*128 + lane]      = da*rs*g[lane]    + b[lane];
    o[(size_t)r*128 + 64 + lane] = dc*rs*g[lane+64] + b[lane+64];
  }
}

// ---------------- sims via MFMA (+ fused sample-column write) ----------------
__global__ void __launch_bounds__(256) k_sims_mfma(
    const unsigned short* __restrict__ kbAh, const unsigned short* __restrict__ kbAl,
    const unsigned short* __restrict__ ckh,  const unsigned short* __restrict__ ckl,
    const float* __restrict__ candn,
    float* __restrict__ sims, float* __restrict__ samp, int ch)
{
  const int tid = threadIdx.x;
  const int wv = tid >> 6, lane = tid & 63;
  const int c0 = blockIdx.x * 64;
  const int q = lane >> 4, n16 = lane & 15;

  f32x4 acc00 = {0.f,0.f,0.f,0.f}, acc01 = {0.f,0.f,0.f,0.f};
  f32x4 acc02 = {0.f,0.f,0.f,0.f}, acc03 = {0.f,0.f,0.f,0.f};
  f32x4 acc10 = {0.f,0.f,0.f,0.f}, acc11 = {0.f,0.f,0.f,0.f};
  f32x4 acc12 = {0.f,0.f,0.f,0.f}, acc13 = {0.f,0.f,0.f,0.f};

  const int mt0 = wv*2, mt1 = wv*2 + 1;
  const size_t a0base = (size_t)(ch*8 + mt0)*2048;
  const size_t a1base = (size_t)(ch*8 + mt1)*2048;
  const size_t b0 = (size_t)(c0 + n16)*128;
  const size_t b1 = b0 + 16*128;
  const size_t b2 = b0 + 32*128;
  const size_t b3 = b0 + 48*128;

#pragma unroll
  for (int s = 0; s < 4; ++s) {
    const size_t ao = (size_t)s*512 + (size_t)lane*8;
    bf16x8 ah0 = *(const bf16x8*)(kbAh + a0base + ao);
    bf16x8 ah1 = *(const bf16x8*)(kbAh + a1base + ao);
    bf16x8 al0 = *(const bf16x8*)(kbAl + a0base + ao);
    bf16x8 al1 = *(const bf16x8*)(kbAl + a1base + ao);
    const int ko = s*32 + q*8;
    bf16x8 bh0v = *(const bf16x8*)(ckh + b0 + ko);
    bf16x8 bh1v = *(const bf16x8*)(ckh + b1 + ko);
    bf16x8 bh2v = *(const bf16x8*)(ckh + b2 + ko);
    bf16x8 bh3v = *(const bf16x8*)(ckh + b3 + ko);
    bf16x8 bl0v = *(const bf16x8*)(ckl + b0 + ko);
    bf16x8 bl1v = *(const bf16x8*)(ckl + b1 + ko);
    bf16x8 bl2v = *(const bf16x8*)(ckl + b2 + ko);
    bf16x8 bl3v = *(const bf16x8*)(ckl + b3 + ko);

    MFMA16(ah0, bh0v, acc00); MFMA16(ah0, bh1v, acc01);
    MFMA16(ah0, bh2v, acc02); MFMA16(ah0, bh3v, acc03);
    MFMA16(ah1, bh0v, acc10); MFMA16(ah1, bh1v, acc11);
    MFMA16(ah1, bh2v, acc12); MFMA16(ah1, bh3v, acc13);

    MFMA16(al0, bh0v, acc00); MFMA16(al0, bh1v, acc01);
    MFMA16(al0, bh2v, acc02); MFMA16(al0, bh3v, acc03);
    MFMA16(al1, bh0v, acc10); MFMA16(al1, bh1v, acc11);
    MFMA16(al1, bh2v, acc12); MFMA16(al1, bh3v, acc13);

    MFMA16(ah0, bl0v, acc00); MFMA16(ah0, bl1v, acc01);
    MFMA16(ah0, bl2v, acc02); MFMA16(ah0, bl3v, acc03);
    MFMA16(ah1, bl0v, acc10); MFMA16(ah1, bl1v, acc11);
    MFMA16(ah1, bl2v, acc12); MFMA16(ah1, bl3v, acc13);
  }

  const int rb0 = mt0*16 + q*4, rb1 = mt1*16 + q*4;
#define EPI(NT, A0, A1) { \
    int col = c0 + NT*16 + n16; \
    if (col < NCAND) { \
      float cn = candn[col]; \
      sims[(size_t)(rb0+0)*NCAND + col] = 2.f*A0[0] - cn; \
      sims[(size_t)(rb0+1)*NCAND + col] = 2.f*A0[1] - cn; \
      sims[(size_t)(rb0+2)*NCAND + col] = 2.f*A0[2] - cn; \
      sims[(size_t)(rb0+3)*NCAND + col] = 2.f*A0[3] - cn; \
      sims[(size_t)(rb1+0)*NCAND + col] = 2.f*A1[0] - cn; \
      sims[(size_t)(rb1+1)*NCAND + col] = 2.f*A1[1] - cn; \
      sims[(size_t)(rb1+2)*NCAND + col] = 2.f*A1[2] - cn; \
      sims[(size_t)(rb1+3)*NCAND + col] = 2.f*A1[3] - cn; \
    } }
  EPI(0, acc00, acc10)
  EPI(1, acc01, acc11)
  EPI(2, acc02, acc12)
  EPI(3, acc03, acc13)
#undef EPI

  if (n16 == 0) {
    float cn0 = candn[c0];
#pragma unroll
    for (int i = 0; i < 4; ++i) {
      samp[(size_t)(rb0+i)*SAMPP + blockIdx.x] = 2.f*acc00[i] - cn0;
      samp[(size_t)(rb1+i)*SAMPP + blockIdx.x] = 2.f*acc10[i] - cn0;
    }
  }
}

// ---------------- select stage 1 (dense sample buffer) ----------------
__global__ void __launch_bounds__(256) k_sample(
    const float* __restrict__ samp, float* __restrict__ gthr, unsigned* __restrict__ gcnt)
{
  __shared__ float sv[NSAMP];
  __shared__ unsigned hist[256];
  __shared__ float wmin[4], wmax[4];
  __shared__ float s_lo, s_inv, s_w;
  const int tid = threadIdx.x, row = blockIdx.x;
  const float* S = samp + (size_t)row*SAMPP;
  float lmax = -__builtin_inff(), lmin = __builtin_inff();
  for (int i = tid; i < NSAMP; i += 256) {
    float v = S[i];
    sv[i] = v;
    lmax = fmaxf(lmax, v); lmin = fminf(lmin, v);
  }
  if (tid < 256) hist[tid] = 0;
  for (int o = 32; o; o >>= 1) {
    lmax = fmaxf(lmax, __shfl_xor(lmax, o));
    lmin = fminf(lmin, __shfl_xor(lmin, o));
  }
  if ((tid & 63) == 0) { wmax[tid>>6] = lmax; wmin[tid>>6] = lmin; }
  __syncthreads();
  if (tid == 0) {
    float hi = wmax[0], lo = wmin[0];
    for (int w = 1; w < 4; ++w) { hi = fmaxf(hi, wmax[w]); lo = fminf(lo, wmin[w]); }
    float rng = hi - lo;
    s_lo = lo;
    s_inv = (rng > 0.f) ? (256.f/rng) : 0.f;
    s_w   = (rng > 0.f) ? (rng/256.f) : 0.f;
  }
  __syncthreads();
  const float lo = s_lo, inv = s_inv;
  for (int i = tid; i < NSAMP; i += 256) {
    int b = min(max((int)((sv[i]-lo)*inv), 0), 255);
    atomicAdd(&hist[b], 1u);
  }
  __syncthreads();
  if (tid == 0) {
    unsigned cum = 0; int b = 255;
    for (; b >= 1; --b) { if (cum + hist[b] >= 24u) break; cum += hist[b]; }
    gthr[row] = lo + (float)b * s_w;
    gcnt[row] = 0u;
  }
}

// ---------------- select stage 2 ----------------
__global__ void __launch_bounds__(256) k_emit(
    const float* __restrict__ sims, const float* __restrict__ gthr,
    unsigned* __restrict__ gcnt, float* __restrict__ ev, int* __restrict__ ei)
{
  __shared__ float lv[BCAP];
  __shared__ int   li[BCAP];
  __shared__ unsigned lcnt, lbase;
  const int tid = threadIdx.x;
  const int row = blockIdx.y;
  const int base = blockIdx.x * 12500;
  const float thr = gthr[row];
  const float* S = sims + (size_t)row*NCAND + base;
  if (tid == 0) lcnt = 0;
  __syncthreads();
  for (int i = tid; i < 3125; i += 256) {
    float4 v = *(const float4*)&S[i*4];
    if (v.x >= thr) { unsigned p = atomicAdd(&lcnt, 1u); if (p < BCAP) { lv[p] = v.x; li[p] = base + i*4 + 0; } }
    if (v.y >= thr) { unsigned p = atomicAdd(&lcnt, 1u); if (p < BCAP) { lv[p] = v.y; li[p] = base + i*4 + 1; } }
    if (v.z >= thr) { unsigned p = atomicAdd(&lcnt, 1u); if (p < BCAP) { lv[p] = v.z; li[p] = base + i*4 + 2; } }
    if (v.w >= thr) { unsigned p = atomicAdd(&lcnt, 1u); if (p < BCAP) { lv[p] = v.w; li[p] = base + i*4 + 3; } }
  }
  __syncthreads();
  const int n = (int)min(lcnt, (unsigned)BCAP);
  if (tid == 0) lbase = atomicAdd(&gcnt[row], (unsigned)n);
  __syncthreads();
  const unsigned gb = lbase;
  float* EV = ev + (size_t)row*EMCAP;
  int*   EI = ei + (size_t)row*EMCAP;
  for (int i = tid; i < n; i += 256) {
    unsigned p = gb + i;
    if (p < EMCAP) { EV[p] = lv[i]; EI[p] = li[i]; }
  }
}

// ---------------- select stage 3 ----------------
__global__ void __launch_bounds__(256) k_final(
    const float* __restrict__ ev, const int* __restrict__ ei,
    const unsigned* __restrict__ gcnt, const float* __restrict__ cand_y,
    float* __restrict__ probs, int* __restrict__ tidxg, float* __restrict__ ygath,
    int r0)
{
  __shared__ float sv[EMCAP];
  __shared__ unsigned hist[1024];
  __shared__ float tv[512]; __shared__ int ti[512];
  __shared__ float selv[96]; __shared__ int seli[96];
  __shared__ unsigned cnts[2];
  __shared__ float wv[4]; __shared__ int wp[4];
  __shared__ float wmin[4], wmax[4];
  __shared__ float s_lo, s_inv;
  __shared__ int sb_s, above_s;
  __shared__ float smax_s, ssum_s;

  const int tid = threadIdx.x, row = blockIdx.x;
  const int n = (int)min(gcnt[row], (unsigned)EMCAP);
  const float* EV = ev + (size_t)row*EMCAP;
  const int*   EI = ei + (size_t)row*EMCAP;

  if (tid < 96) { selv[tid] = -1e30f; seli[tid] = 0; }
  for (int i = tid; i < 1024; i += 256) hist[i] = 0;
  if (tid < 2) cnts[tid] = 0;

  float lmax = -__builtin_inff(), lmin = __builtin_inff();
  for (int i = tid; i < n; i += 256) {
    float v = EV[i]; sv[i] = v;
    lmax = fmaxf(lmax, v); lmin = fminf(lmin, v);
  }
  for (int o = 32; o; o >>= 1) {
    lmax = fmaxf(lmax, __shfl_xor(lmax, o));
    lmin = fminf(lmin, __shfl_xor(lmin, o));
  }
  if ((tid & 63) == 0) { wmax[tid>>6] = lmax; wmin[tid>>6] = lmin; }
  __syncthreads();
  if (tid == 0) {
    float hi = wmax[0], lo = wmin[0];
    for (int w2 = 1; w2 < 4; ++w2) { hi = fmaxf(hi, wmax[w2]); lo = fminf(lo, wmin[w2]); }
    float rng = hi - lo;
    s_lo = lo; s_inv = (rng > 0.f) ? (1024.f/rng) : 0.f;
  }
  __syncthreads();
  const float lo = s_lo, inv = s_inv;

  for (int i = tid; i < n; i += 256) {
    int b = min(max((int)((sv[i]-lo)*inv), 0), 1023);
    atomicAdd(&hist[b], 1u);
  }
  __syncthreads();
  if (tid == 0) {
    unsigned cum = 0; int b = 1023;
    for (; b >= 1; --b) { if (cum + hist[b] >= 96u) break; cum += hist[b]; }
    sb_s = b; above_s = (int)cum;
  }
  __syncthreads();
  const int sb = sb_s, above = above_s;

  for (int i = tid; i < n; i += 256) {
    float v = sv[i];
    int b = min(max((int)((v-lo)*inv), 0), 1023);
    if (b > sb) {
      unsigned p = atomicAdd(&cnts[0], 1u);
      if (p < 96u) { selv[p] = v; seli[p] = EI[i]; }
    } else if (b == sb) {
      unsigned p = atomicAdd(&cnts[1], 1u);
      if (p < 512u) { tv[p] = v; ti[p] = EI[i]; }
    }
  }
  __syncthreads();
  const int need = 96 - above;
  const int tcnt = (int)min(cnts[1], 512u);
  for (int rd = 0; rd < need; ++rd) {
    float best = -__builtin_inff(); int bp = -1;
    for (int t = tid; t < tcnt; t += 256) {
      float v = tv[t];
      if (v > best) { best = v; bp = t; }
    }
    for (int o = 32; o; o >>= 1) {
      float ob = __shfl_xor(best, o); int obp = __shfl_xor(bp, o);
      if (ob > best) { best = ob; bp = obp; }
    }
    if ((tid & 63) == 0) { wv[tid>>6] = best; wp[tid>>6] = bp; }
    __syncthreads();
    if (tid == 0) {
      float bb = wv[0]; int pp = wp[0];
      for (int w2 = 1; w2 < 4; ++w2) if (wv[w2] > bb) { bb = wv[w2]; pp = wp[w2]; }
      if (pp >= 0) { selv[above + rd] = bb; seli[above + rd] = ti[pp]; tv[pp] = -__builtin_inff(); }
    }
    __syncthreads();
  }

  if (tid == 0) {
    float m = selv[0];
    for (int i = 1; i < 96; ++i) m = fmaxf(m, selv[i]);
    smax_s = m;
  }
  __syncthreads();
  if (tid < 96) selv[tid] = expf(selv[tid] - smax_s);
  __syncthreads();
  if (tid == 0) {
    float s = 0.f;
    for (int i = 0; i < 96; ++i) s += selv[i];
    ssum_s = s;
  }
  __syncthreads();
  if (tid < 96) {
    int gr = r0 + row;
    int gi = seli[tid];
    probs[(size_t)gr*96 + tid] = selv[tid]/ssum_s;
    tidxg[(size_t)gr*96 + tid] = gi;
    ygath[(size_t)gr*96 + tid] = cand_y[gi];
  }
}

// ---------------- context accumulation ----------------
__global__ void __launch_bounds__(128) k_ctx(
    const float* __restrict__ probs, const float* __restrict__ ygath,
    const float* __restrict__ t2, const float* __restrict__ x2b,
    const float* __restrict__ w_le, const float* __restrict__ b_le,
    float* __restrict__ xfinal)
{
  int bb = blockIdx.x;
  int d = threadIdx.x;
  float wle = w_le[d], ble = b_le[d];
  float acc = 0.f;
  for (int c = 0; c < 96; ++c) {
    float p = probs[(size_t)bb*96 + c];
    float y = ygath[(size_t)bb*96 + c];
    acc += p*(y*wle + ble + t2[(size_t)(bb*96 + c)*128 + d]);
  }
  xfinal[(size_t)bb*128 + d] = x2b[(size_t)bb*128 + d] + acc;
}

// ---------------- head ----------------
__global__ void __launch_bounds__(256) k_head(
    const float* __restrict__ x, const float* __restrict__ g, const float* __restrict__ b,
    const float* __restrict__ Wh, const float* __restrict__ bh,
    float* __restrict__ out, int M)
{
  const int lane = threadIdx.x & 63, w = threadIdx.x >> 6;
  int rb = blockIdx.x*32 + w*8;
  for (int it = 0; it < 8; ++it) {
    int r = rb + it;
    if (r >= M) return;
    float a = x[(size_t)r*128 + lane];
    float c = x[(size_t)r*128 + 64 + lane];
    float s = a + c;
    for (int o = 32; o; o >>= 1) s += __shfl_xor(s, o);
    float mu = s*(1.f/128.f);
    float da = a - mu, dc = c - mu;
    float v = da*da + dc*dc;
    for (int o = 32; o; o >>= 1) v += __shfl_xor(v, o);
    float rs = rsqrtf(v*(1.f/128.f) + 1e-5f);
    float l0 = fmaxf(da*rs*g[lane]    + b[lane],    0.f);
    float l1 = fmaxf(dc*rs*g[lane+64] + b[lane+64], 0.f);
    float p0 = l0*Wh[lane]     + l1*Wh[64+lane];
    float p1 = l0*Wh[128+lane] + l1*Wh[192+lane];
    for (int o = 32; o; o >>= 1) { p0 += __shfl_xor(p0, o); p1 += __shfl_xor(p1, o); }
    if (lane == 0) { out[r*2 + 0] = p0 + bh[0]; out[r*2 + 1] = p1 + bh[1]; }
  }
}

// ---------------- launcher ----------------
extern "C" void kernel_launch(void* const* d_in, const int* in_sizes, int n_in,
                              void* d_out, int out_size, void* d_ws, size_t ws_size,
                              hipStream_t stream) {
  const float* x_num   = (const float*)d_in[0];
  const float* cand_x  = (const float*)d_in[1];
  const float* cand_y  = (const float*)d_in[2];
  const float* W_in    = (const float*)d_in[3];
  const float* b_in    = (const float*)d_in[4];
  const float* enc_W1  = (const float*)d_in[5];
  const float* enc_b1  = (const float*)d_in[6];
  const float* enc_W2  = (const float*)d_in[7];
  const float* enc_b2  = (const float*)d_in[8];
  const float* mix_g   = (const float*)d_in[9];
  const float* mix_b   = (const float*)d_in[10];
  const float* W_k     = (const float*)d_in[11];
  const float* b_k     = (const float*)d_in[12];
  const float* w_le    = (const float*)d_in[13];
  const float* b_le    = (const float*)d_in[14];
  const float* W_t1    = (const float*)d_in[15];
  const float* b_t1    = (const float*)d_in[16];
  const float* W_t2    = (const float*)d_in[17];
  const float* pred_g  = (const float*)d_in[18];
  const float* pred_b  = (const float*)d_in[19];
  const float* pred_W1 = (const float*)d_in[20];
  const float* pred_b1 = (const float*)d_in[21];
  const float* pred_W2 = (const float*)d_in[22];
  const float* pred_b2 = (const float*)d_in[23];
  const float* head_g  = (const float*)d_in[24];
  const float* head_b  = (const float*)d_in[25];
  const float* W_head  = (const float*)d_in[26];
  const float* b_head  = (const float*)d_in[27];

  float* ws  = (float*)d_ws;
  float* out = (float*)d_out;

  float*          wt     = ws;
  unsigned short* Wh     = (unsigned short*)ws;
  unsigned short* Wl     = Wh + 155648;
  unsigned short* ckh    = (unsigned short*)(ws + OFF_CKH);
  unsigned short* ckl    = (unsigned short*)(ws + OFF_CKL);
  float*          candn  = ws + OFF_CANDN;
  float*          kb     = ws + OFF_KB;
  float*          x2b    = ws + OFF_X2B;
  float*          lnb    = ws + OFF_LNB;
  float*          hb     = ws + OFF_HB;
  float*          xpred  = ws + OFF_XPRED;
  float*          xfin   = ws + OFF_XFIN;
  unsigned short* kbAh   = (unsigned short*)(ws + OFF_KBA);
  unsigned short* kbAl   = kbAh + 131072;
  float*          probs  = ws + OFF_PROBS;
  int*            tidxg  = (int*)(ws + OFF_TIDX);
  float*          ygath  = ws + OFF_YG;
  float*          simsbuf = ws + OFF_SX;
  float*          t2buf  = ws + OFF_SX;
  float*          ev     = ws + OFF_EV;
  int*            ei     = (int*)(ws + OFF_EI);
  unsigned*       gcnt   = (unsigned*)(ws + OFF_GCNT);
  float*          gthr   = ws + OFF_GTHR;
  float*          samp   = ws + OFF_SAMP;

  // 1) weight prep
  k_cvt_w<<<96, 256, 0, stream>>>(W_in, enc_W1, enc_W2, W_k, W_t1, W_t2, Wh, Wl);
  k_transpose<<<64, 256, 0, stream>>>(pred_W1, pred_W2, wt);
  k_pad_ck<<<16, 256, 0, stream>>>(ckh, ckl);

  // 2) batch encoder (fused v5) -> x2b, kb; then kb -> A-frags
  k_enc_fused<true><<<BATCH/128, 256, 0, stream>>>(
      x_num, Wh, Wl, b_in, enc_b1, enc_b2, mix_g, mix_b, b_k,
      nullptr, nullptr, nullptr, x2b, kb, BATCH);
  k_cvt_kbA<<<512, 256, 0, stream>>>(kb, kbAh, kbAl);

  // 3) candidate encoder (fused v5) -> ckh/ckl, candn
  k_enc_fused<false><<<(NCAND+127)/128, 256, 0, stream>>>(
      cand_x, Wh, Wl, b_in, enc_b1, enc_b2, mix_g, mix_b, b_k,
      ckh, ckl, candn, nullptr, nullptr, NCAND);

  // 4) sims (MFMA, fused sample) + exact top-96, 8 row chunks of 128
  for (int ch = 0; ch < 8; ++ch) {
    k_sims_mfma<<<NCPAD/64, 256, 0, stream>>>(kbAh, kbAl, ckh, ckl, candn, simsbuf, samp, ch);
    k_sample<<<RCH, 256, 0, stream>>>(samp, gthr, gcnt);
    k_emit<<<dim3(8, RCH), 256, 0, stream>>>(simsbuf, gthr, gcnt, ev, ei);
    k_final<<<RCH, 256, 0, stream>>>(ev, ei, gcnt, cand_y, probs, tidxg, ygath, ch*RCH);
  }

  // 5) t-net (fused MFMA) + context
  k_tnet<<<NPAIR/64, 256, 0, stream>>>(kb, ckh, ckl, tidxg, Wh, Wl, b_t1, t2buf);
  k_ctx<<<BATCH, 128, 0, stream>>>(probs, ygath, t2buf, x2b, w_le, b_le, xfin);

  // 6) predictor block + head
  k_ln<<<(BATCH+31)/32, 256, 0, stream>>>(xfin, pred_g, pred_b, lnb, BATCH);
  k_gemm<256,true ,false><<<16, 256, 0, stream>>>(lnb, wt+WT_P1, pred_b1, nullptr, hb,    BATCH, 128);
  k_gemm<128,false,true ><<<16, 256, 0, stream>>>(hb,  wt+WT_P2, pred_b2, xfin,    xpred, BATCH, 256);
  k_head<<<(BATCH+31)/32, 256, 0, stream>>>(xpred, head_g, head_b, W_head, b_head, out, BATCH);
}

// Round 12
// 878.032 us; speedup vs baseline: 1.7844x; 1.4523x over previous
//
#include <hip/hip_runtime.h>
#include <math.h>

// ---------------- problem sizes ----------------
#define BATCH   1024
#define NCAND   100000
#define NCPAD   100032
#define DM      128
#define DB      256
#define NNUM    64
#define CTXS    96
#define NPAIR   (BATCH*CTXS)   // 98304
#define EMCAP   6144
#define TCAP    24             // per-row per-64-cand-tile emit cap
#define NSAMP   1563
#define SAMPP   1600

// ---------------- workspace offsets (floats) ----------------
#define WB_IN       0u
#define WB_E1       8192u
#define WB_E2       40960u
#define WB_K        73728u
#define WB_T1       90112u
#define WB_T2       122880u
#define WT_P1       155648u
#define WT_P2       188416u
#define OFF_CKH     221184u      // 100032*128 bf16 hi
#define OFF_CKL     6623232u     // 100032*128 bf16 lo
#define OFF_CANDN   13025280u
#define OFF_KB      13125280u
#define OFF_X2B     13387424u
#define OFF_LNB     13518496u
#define OFF_HB      13649568u
#define OFF_XPRED   13911712u
#define OFF_XFIN    14042784u
#define OFF_KBA     14173856u
#define OFF_PROBS   15743648u
#define OFF_TIDX    15841952u
#define OFF_YG      15940256u
#define OFF_EV      16038560u    // 1024*6144 floats (select) / t2buf (t-net) overlap
#define OFF_EI      22330016u    // 1024*6144 int
#define OFF_SAMP    28621472u    // 1024*1600 floats (ends 30,259,872)
#define OFF_GCNT    30935712u    // 1024*16 uint (64B-padded counters, ends 30,952,096)
#define OFF_GTHR    30952096u    // 1024 floats (FIXED: no longer overlaps gcnt)

typedef __attribute__((ext_vector_type(8))) short bf16x8;
typedef __attribute__((ext_vector_type(4))) float f32x4;
#define MFMA16(A,B,C) C = __builtin_amdgcn_mfma_f32_16x16x32_bf16(A, B, C, 0, 0, 0)

__device__ __forceinline__ unsigned short f2bf(float x) {
  unsigned u = __float_as_uint(x);
  unsigned r = (u + 0x7FFFu + ((u >> 16) & 1u)) >> 16;
  return (unsigned short)r;
}
__device__ __forceinline__ float bf2f(unsigned short h) {
  return __uint_as_float(((unsigned)h) << 16);
}

// ---------------- prep ----------------
__global__ void __launch_bounds__(256) k_transpose(
    const float* __restrict__ w0, const float* __restrict__ w1,
    float* __restrict__ dst)
{
  const float* src[2] = {w0,w1};
  const int nn[2]  = {256,128};
  const int kkv[2] = {128,256};
  const int off[2] = {155648,188416};
  int stride = gridDim.x*blockDim.x;
  int t0 = blockIdx.x*blockDim.x + threadIdx.x;
#pragma unroll
  for (int m = 0; m < 2; ++m) {
    int total = nn[m]*kkv[m];
    for (int i = t0; i < total; i += stride) {
      int k = i / nn[m];
      int n = i - k*nn[m];
      dst[off[m] + i] = src[m][n*kkv[m] + k];
    }
  }
}

// weights -> bf16 hi/lo in B-frag slice-major order
__global__ void __launch_bounds__(256) k_cvt_w(
    const float* __restrict__ w_in, const float* __restrict__ e1,
    const float* __restrict__ e2, const float* __restrict__ wk,
    const float* __restrict__ t1, const float* __restrict__ t2,
    unsigned short* __restrict__ Wh, unsigned short* __restrict__ Wl)
{
  const float* src[6] = {w_in, e1, e2, wk, t1, t2};
  const int NN[6] = {128, 256, 128, 128, 256, 128};
  const int KK[6] = { 64, 128, 256, 128, 128, 256};
  const int off[6] = {WB_IN, WB_E1, WB_E2, WB_K, WB_T1, WB_T2};
  int stride = gridDim.x*blockDim.x;
  int t0 = blockIdx.x*blockDim.x + threadIdx.x;
#pragma unroll
  for (int m = 0; m < 6; ++m) {
    const int NT = NN[m] >> 4;
    const int K = KK[m];
    const int total = NN[m]*K;
    for (int i = t0; i < total; i += stride) {
      int j = i & 7;
      int lane = (i >> 3) & 63;
      int rem = i >> 9;
      int nt = rem % NT, ks = rem / NT;
      int row = nt*16 + (lane & 15);
      int col = ks*32 + (lane >> 4)*8 + j;
      float x = src[m][row*K + col];
      unsigned short h = f2bf(x);
      Wh[off[m]+i] = h;
      Wl[off[m]+i] = f2bf(x - bf2f(h));
    }
  }
}

__global__ void __launch_bounds__(256) k_pad_ck(
    unsigned short* __restrict__ ckh, unsigned short* __restrict__ ckl)
{
  int i = blockIdx.x*256 + threadIdx.x;
  if (i < 4096) {
    ckh[(size_t)NCAND*128 + i] = 0;
    ckl[(size_t)NCAND*128 + i] = 0;
  }
}

__global__ void __launch_bounds__(256) k_cvt_kbA(
    const float* __restrict__ kb,
    unsigned short* __restrict__ kbAh, unsigned short* __restrict__ kbAl)
{
  int i = blockIdx.x*256 + threadIdx.x;
  int j = i & 7, lane = (i >> 3) & 63, s = (i >> 9) & 3, mt = (i >> 11) & 7, ch = i >> 14;
  int row = ch*128 + mt*16 + (lane & 15);
  int k = s*32 + (lane >> 4)*8 + j;
  float x = kb[(size_t)row*128 + k];
  unsigned short h = f2bf(x);
  kbAh[i] = h;
  kbAl[i] = f2bf(x - bf2f(h));
}

// ---------------- FUSED ENCODER v5 (R10-proven) ----------------
template<bool BATCHOUT>
__global__ void __launch_bounds__(256, 2) k_enc_fused(
    const float* __restrict__ xnum,
    const unsigned short* __restrict__ Wh, const unsigned short* __restrict__ Wl,
    const float* __restrict__ b_in, const float* __restrict__ b1,
    const float* __restrict__ b2, const float* __restrict__ mix_g,
    const float* __restrict__ mix_b, const float* __restrict__ b_k,
    unsigned short* __restrict__ ckh, unsigned short* __restrict__ ckl,
    float* __restrict__ candn,
    float* __restrict__ x2out, float* __restrict__ kout,
    int M)
{
  __shared__ __align__(16) unsigned short sAct[32768];
  __shared__ __align__(16) unsigned short sWt[32768];
  const int tid = threadIdx.x;
  const int wv = tid >> 6, lane = tid & 63;
  const int q = lane >> 4, n16 = lane & 15;
  const int r0 = blockIdx.x * 128;
  unsigned short* wbuf = sAct + wv*8192;

  auto stageW = [&](unsigned base, int NT, int ks, int slot) {
    const int n = NT*64;
    const unsigned short* sh = Wh + base + (size_t)ks*n*8;
    const unsigned short* sl = Wl + base + (size_t)ks*n*8;
    unsigned short* dh = sWt + slot*16384;
    unsigned short* dl = dh + 8192;
    for (int i = tid; i < n; i += 256) {
      *(bf16x8*)(dh + i*8) = *(const bf16x8*)(sh + i*8);
      *(bf16x8*)(dl + i*8) = *(const bf16x8*)(sl + i*8);
    }
  };

  bf16x8 xa_h[2][2], xa_l[2][2];
#pragma unroll
  for (int mt = 0; mt < 2; ++mt) {
#pragma unroll
    for (int ks = 0; ks < 2; ++ks) {
      int row = r0 + wv*32 + mt*16 + n16;
      int k0 = ks*32 + q*8;
      float4 p0 = {0.f,0.f,0.f,0.f}, p1 = {0.f,0.f,0.f,0.f};
      if (row < M) {
        p0 = *(const float4*)&xnum[(size_t)row*64 + k0];
        p1 = *(const float4*)&xnum[(size_t)row*64 + k0 + 4];
      }
#define CV(di, val) { unsigned short hh = f2bf(val); xa_h[mt][ks][di] = (short)hh; xa_l[mt][ks][di] = (short)f2bf((val) - bf2f(hh)); }
      CV(0,p0.x) CV(1,p0.y) CV(2,p0.z) CV(3,p0.w) CV(4,p1.x) CV(5,p1.y) CV(6,p1.z) CV(7,p1.w)
#undef CV
    }
  }

  f32x4 xc[2][8];
#pragma unroll
  for (int mt = 0; mt < 2; ++mt)
#pragma unroll
    for (int nt = 0; nt < 8; ++nt) {
      float b = b_in[nt*16 + n16];
      xc[mt][nt][0]=b; xc[mt][nt][1]=b; xc[mt][nt][2]=b; xc[mt][nt][3]=b;
    }
  stageW(WB_IN, 8, 0, 0);
  __syncthreads();
  for (int ks = 0; ks < 2; ++ks) {
    if (ks == 0) stageW(WB_IN, 8, 1, 1);
    const unsigned short* wh = sWt + (ks&1)*16384;
#pragma unroll
    for (int nt = 0; nt < 8; ++nt) {
      bf16x8 bh = *(const bf16x8*)(wh + (nt*64+lane)*8);
      bf16x8 bl = *(const bf16x8*)(wh + 8192 + (nt*64+lane)*8);
      MFMA16(xa_h[0][ks], bh, xc[0][nt]); MFMA16(xa_l[0][ks], bh, xc[0][nt]); MFMA16(xa_h[0][ks], bl, xc[0][nt]);
      MFMA16(xa_h[1][ks], bh, xc[1][nt]); MFMA16(xa_l[1][ks], bh, xc[1][nt]); MFMA16(xa_h[1][ks], bl, xc[1][nt]);
    }
    __syncthreads();
  }

#pragma unroll
  for (int mt = 0; mt < 2; ++mt)
#pragma unroll
    for (int nt = 0; nt < 8; ++nt) {
      int col = nt*16 + n16;
      int ks2 = col >> 5, q2 = (col >> 3) & 3, j2 = col & 7;
#pragma unroll
      for (int i = 0; i < 4; ++i) {
        int idx = (mt*4 + ks2)*512 + (q2*16 + q*4 + i)*8 + j2;
        float v = xc[mt][nt][i];
        unsigned short hh = f2bf(v);
        wbuf[idx] = hh;
        wbuf[4096 + idx] = f2bf(v - bf2f(hh));
      }
    }

  f32x4 hc[2][16];
#pragma unroll
  for (int mt = 0; mt < 2; ++mt)
#pragma unroll
    for (int nt = 0; nt < 16; ++nt) { hc[mt][nt][0]=0.f; hc[mt][nt][1]=0.f; hc[mt][nt][2]=0.f; hc[mt][nt][3]=0.f; }
  stageW(WB_E1, 16, 0, 0);
  __syncthreads();
  for (int ks = 0; ks < 4; ++ks) {
    if (ks < 3) stageW(WB_E1, 16, ks+1, (ks+1)&1);
    const unsigned short* wh = sWt + (ks&1)*16384;
    bf16x8 ah0 = *(const bf16x8*)(wbuf + (0*4+ks)*512 + lane*8);
    bf16x8 al0 = *(const bf16x8*)(wbuf + 4096 + (0*4+ks)*512 + lane*8);
    bf16x8 ah1 = *(const bf16x8*)(wbuf + (1*4+ks)*512 + lane*8);
    bf16x8 al1 = *(const bf16x8*)(wbuf + 4096 + (1*4+ks)*512 + lane*8);
#pragma unroll
    for (int nt = 0; nt < 16; ++nt) {
      bf16x8 bh = *(const bf16x8*)(wh + (nt*64+lane)*8);
      bf16x8 bl = *(const bf16x8*)(wh + 8192 + (nt*64+lane)*8);
      MFMA16(ah0, bh, hc[0][nt]); MFMA16(al0, bh, hc[0][nt]); MFMA16(ah0, bl, hc[0][nt]);
      MFMA16(ah1, bh, hc[1][nt]); MFMA16(al1, bh, hc[1][nt]); MFMA16(ah1, bl, hc[1][nt]);
    }
    __syncthreads();
  }

  f32x4 x2c[2][8];
#pragma unroll
  for (int mt = 0; mt < 2; ++mt)
#pragma unroll
    for (int nt = 0; nt < 8; ++nt) {
      float b = b2[nt*16 + n16];
      int col = nt*16 + n16;
      int ks2 = col >> 5, q2 = (col >> 3) & 3, j2 = col & 7;
#pragma unroll
      for (int i = 0; i < 4; ++i) {
        int idx = (mt*4 + ks2)*512 + (q2*16 + q*4 + i)*8 + j2;
        x2c[mt][nt][i] = b + bf2f(wbuf[idx]) + bf2f(wbuf[4096 + idx]);
      }
    }
#pragma unroll
  for (int mt = 0; mt < 2; ++mt)
#pragma unroll
    for (int nt = 0; nt < 16; ++nt) {
      float b = b1[nt*16 + n16];
      int col = nt*16 + n16;
      int ks2 = col >> 5, q2 = (col >> 3) & 3, j2 = col & 7;
#pragma unroll
      for (int i = 0; i < 4; ++i) {
        float v = fmaxf(hc[mt][nt][i] + b, 0.f);
        wbuf[(mt*8 + ks2)*512 + (q2*16 + q*4 + i)*8 + j2] = f2bf(v);
      }
    }

  stageW(WB_E2, 8, 0, 0);
  __syncthreads();
  for (int ks = 0; ks < 8; ++ks) {
    if (ks < 7) stageW(WB_E2, 8, ks+1, (ks+1)&1);
    const unsigned short* wh = sWt + (ks&1)*16384;
    bf16x8 ha0 = *(const bf16x8*)(wbuf + (0*8+ks)*512 + lane*8);
    bf16x8 ha1 = *(const bf16x8*)(wbuf + (1*8+ks)*512 + lane*8);
#pragma unroll
    for (int nt = 0; nt < 8; ++nt) {
      bf16x8 bh = *(const bf16x8*)(wh + (nt*64+lane)*8);
      bf16x8 bl = *(const bf16x8*)(wh + 8192 + (nt*64+lane)*8);
      MFMA16(ha0, bh, x2c[0][nt]); MFMA16(ha0, bl, x2c[0][nt]);
      MFMA16(ha1, bh, x2c[1][nt]); MFMA16(ha1, bl, x2c[1][nt]);
    }
    __syncthreads();
  }
  if constexpr (BATCHOUT) {
#pragma unroll
    for (int mt = 0; mt < 2; ++mt)
#pragma unroll
      for (int nt = 0; nt < 8; ++nt) {
        int col = nt*16 + n16;
#pragma unroll
        for (int i = 0; i < 4; ++i) {
          int row = r0 + wv*32 + mt*16 + q*4 + i;
          if (row < M) x2out[(size_t)row*128 + col] = x2c[mt][nt][i];
        }
      }
  }

#pragma unroll
  for (int mt = 0; mt < 2; ++mt) {
#pragma unroll
    for (int i = 0; i < 4; ++i) {
      float s = 0.f;
#pragma unroll
      for (int nt = 0; nt < 8; ++nt) s += x2c[mt][nt][i];
      s += __shfl_xor(s, 1); s += __shfl_xor(s, 2); s += __shfl_xor(s, 4); s += __shfl_xor(s, 8);
      float mu = s * (1.f/128.f);
      float v = 0.f;
#pragma unroll
      for (int nt = 0; nt < 8; ++nt) { float d = x2c[mt][nt][i] - mu; v += d*d; }
      v += __shfl_xor(v, 1); v += __shfl_xor(v, 2); v += __shfl_xor(v, 4); v += __shfl_xor(v, 8);
      float rs = rsqrtf(v*(1.f/128.f) + 1e-5f);
#pragma unroll
      for (int nt = 0; nt < 8; ++nt) {
        float lv = (x2c[mt][nt][i] - mu)*rs*mix_g[nt*16 + n16] + mix_b[nt*16 + n16];
        int col = nt*16 + n16;
        int ks2 = col >> 5, q2 = (col >> 3) & 3, j2 = col & 7;
        int idx = (mt*4 + ks2)*512 + (q2*16 + q*4 + i)*8 + j2;
        unsigned short hh = f2bf(lv);
        wbuf[idx] = hh;
        wbuf[4096 + idx] = f2bf(lv - bf2f(hh));
      }
    }
  }

  f32x4 kc[2][8];
#pragma unroll
  for (int mt = 0; mt < 2; ++mt)
#pragma unroll
    for (int nt = 0; nt < 8; ++nt) {
      float b = b_k[nt*16 + n16];
      kc[mt][nt][0]=b; kc[mt][nt][1]=b; kc[mt][nt][2]=b; kc[mt][nt][3]=b;
    }
  stageW(WB_K, 8, 0, 0);
  __syncthreads();
  for (int ks = 0; ks < 4; ++ks) {
    if (ks < 3) stageW(WB_K, 8, ks+1, (ks+1)&1);
    const unsigned short* wh = sWt + (ks&1)*16384;
    bf16x8 ah0 = *(const bf16x8*)(wbuf + (0*4+ks)*512 + lane*8);
    bf16x8 al0 = *(const bf16x8*)(wbuf + 4096 + (0*4+ks)*512 + lane*8);
    bf16x8 ah1 = *(const bf16x8*)(wbuf + (1*4+ks)*512 + lane*8);
    bf16x8 al1 = *(const bf16x8*)(wbuf + 4096 + (1*4+ks)*512 + lane*8);
#pragma unroll
    for (int nt = 0; nt < 8; ++nt) {
      bf16x8 bh = *(const bf16x8*)(wh + (nt*64+lane)*8);
      bf16x8 bl = *(const bf16x8*)(wh + 8192 + (nt*64+lane)*8);
      MFMA16(ah0, bh, kc[0][nt]); MFMA16(al0, bh, kc[0][nt]); MFMA16(ah0, bl, kc[0][nt]);
      MFMA16(ah1, bh, kc[1][nt]); MFMA16(al1, bh, kc[1][nt]); MFMA16(ah1, bl, kc[1][nt]);
    }
    __syncthreads();
  }

#pragma unroll
  for (int mt = 0; mt < 2; ++mt) {
#pragma unroll
    for (int i = 0; i < 4; ++i) {
      int row = r0 + wv*32 + mt*16 + q*4 + i;
      if constexpr (!BATCHOUT) {
        float s2 = 0.f;
#pragma unroll
        for (int nt = 0; nt < 8; ++nt) { float kv = kc[mt][nt][i]; s2 += kv*kv; }
        s2 += __shfl_xor(s2, 1); s2 += __shfl_xor(s2, 2); s2 += __shfl_xor(s2, 4); s2 += __shfl_xor(s2, 8);
        if (n16 == 0 && row < M) candn[row] = s2;
      }
#pragma unroll
      for (int nt = 0; nt < 8; ++nt) {
        int col = nt*16 + n16;
        float kv = kc[mt][nt][i];
        if (row < M) {
          if constexpr (BATCHOUT) {
            kout[(size_t)row*128 + col] = kv;
          } else {
            unsigned short hh = f2bf(kv);
            ckh[(size_t)row*128 + col] = hh;
            ckl[(size_t)row*128 + col] = f2bf(kv - bf2f(hh));
          }
        }
      }
    }
  }
}

// ---------------- FUSED T-NET ----------------
__global__ void __launch_bounds__(256) k_tnet(
    const float* __restrict__ kb,
    const unsigned short* __restrict__ ckh, const unsigned short* __restrict__ ckl,
    const int* __restrict__ tidxg,
    const unsigned short* __restrict__ Wh, const unsigned short* __restrict__ Wl,
    const float* __restrict__ b_t1, float* __restrict__ t2out)
{
  __shared__ __align__(16) unsigned short sBuf[16384];
  const int tid = threadIdx.x;
  const int wv = tid >> 6, lane = tid & 63;
  const int q = lane >> 4, n16 = lane & 15;
  const int p0 = blockIdx.x * 64;
  unsigned short* wbuf = sBuf + wv*4096;

#pragma unroll
  for (int ks = 0; ks < 4; ++ks) {
    int m = lane & 15, qq = lane >> 4;
    int gp = p0 + wv*16 + m;
    int d  = ks*32 + qq*8;
    int idx = tidxg[gp];
    idx = (idx >= 0 && idx < NCAND) ? idx : 0;   // defensive clamp
    int bb  = gp / 96;
    bf16x8 h8 = *(const bf16x8*)(ckh + (size_t)idx*128 + d);
    bf16x8 l8 = *(const bf16x8*)(ckl + (size_t)idx*128 + d);
    float4 k0 = *(const float4*)&kb[(size_t)bb*128 + d];
    float4 k1 = *(const float4*)&kb[(size_t)bb*128 + d + 4];
    bf16x8 df;
    df[0] = (short)f2bf(k0.x - (bf2f(h8[0]) + bf2f(l8[0])));
    df[1] = (short)f2bf(k0.y - (bf2f(h8[1]) + bf2f(l8[1])));
    df[2] = (short)f2bf(k0.z - (bf2f(h8[2]) + bf2f(l8[2])));
    df[3] = (short)f2bf(k0.w - (bf2f(h8[3]) + bf2f(l8[3])));
    df[4] = (short)f2bf(k1.x - (bf2f(h8[4]) + bf2f(l8[4])));
    df[5] = (short)f2bf(k1.y - (bf2f(h8[5]) + bf2f(l8[5])));
    df[6] = (short)f2bf(k1.z - (bf2f(h8[6]) + bf2f(l8[6])));
    df[7] = (short)f2bf(k1.w - (bf2f(h8[7]) + bf2f(l8[7])));
    *(bf16x8*)(wbuf + ks*512 + lane*8) = df;
  }

  f32x4 hc[16];
#pragma unroll
  for (int nt = 0; nt < 16; ++nt) { hc[nt][0]=0.f; hc[nt][1]=0.f; hc[nt][2]=0.f; hc[nt][3]=0.f; }
#pragma unroll
  for (int ks = 0; ks < 4; ++ks) {
    bf16x8 ad = *(const bf16x8*)(wbuf + ks*512 + lane*8);
#pragma unroll
    for (int nt = 0; nt < 16; ++nt) {
      size_t wo = WB_T1 + (size_t)((ks*16 + nt)*64 + lane)*8;
      bf16x8 bh = *(const bf16x8*)(Wh + wo);
      bf16x8 bl = *(const bf16x8*)(Wl + wo);
      MFMA16(ad, bh, hc[nt]); MFMA16(ad, bl, hc[nt]);
    }
  }
#pragma unroll
  for (int nt = 0; nt < 16; ++nt) {
    float b = b_t1[nt*16 + n16];
    int col = nt*16 + n16;
    int ks2 = col >> 5, q2 = (col >> 3) & 3, j2 = col & 7;
#pragma unroll
    for (int i = 0; i < 4; ++i) {
      float v = fmaxf(hc[nt][i] + b, 0.f);
      wbuf[ks2*512 + (q2*16 + q*4 + i)*8 + j2] = f2bf(v);
    }
  }

  f32x4 tc[8];
#pragma unroll
  for (int nt = 0; nt < 8; ++nt) { tc[nt][0]=0.f; tc[nt][1]=0.f; tc[nt][2]=0.f; tc[nt][3]=0.f; }
#pragma unroll
  for (int ks = 0; ks < 8; ++ks) {
    bf16x8 ha = *(const bf16x8*)(wbuf + ks*512 + lane*8);
#pragma unroll
    for (int nt = 0; nt < 8; ++nt) {
      size_t wo = WB_T2 + (size_t)((ks*8 + nt)*64 + lane)*8;
      bf16x8 bh = *(const bf16x8*)(Wh + wo);
      bf16x8 bl = *(const bf16x8*)(Wl + wo);
      MFMA16(ha, bh, tc[nt]); MFMA16(ha, bl, tc[nt]);
    }
  }
#pragma unroll
  for (int nt = 0; nt < 8; ++nt) {
    int col = nt*16 + n16;
#pragma unroll
    for (int i = 0; i < 4; ++i) {
      int pr = p0 + wv*16 + q*4 + i;
      t2out[(size_t)pr*128 + col] = tc[nt][i];
    }
  }
}

// ---------------- generic fp32 GEMM (predictor) ----------------
template<int N, bool RELU, bool RESID>
__global__ void __launch_bounds__(256) k_gemm(
    const float* __restrict__ A, const float* __restrict__ WT,
    const float* __restrict__ bias, const float* __restrict__ resid,
    float* __restrict__ C, int M, int K)
{
  constexpr int G = N/64;
  __shared__ __align__(16) float sA[64*33];
  __shared__ __align__(16) float sW[32*N];
  const int tid = threadIdx.x;
  const int r0 = blockIdx.x*64;
  const int tr = tid >> 4, tc = tid & 15;
  float acc[4][G*4];
#pragma unroll
  for (int i = 0; i < 4; ++i)
#pragma unroll
    for (int j = 0; j < G*4; ++j) acc[i][j] = 0.f;

  for (int kc = 0; kc < K; kc += 32) {
    for (int i = tid; i < 64*32; i += 256) {
      int r = i >> 5, kk = i & 31;
      int gr = r0 + r;
      sA[r*33 + kk] = (gr < M) ? A[(size_t)gr*K + kc + kk] : 0.f;
    }
    for (int i = tid; i < 32*N; i += 256) sW[i] = WT[(size_t)kc*N + i];
    __syncthreads();
    for (int kk = 0; kk < 32; ++kk) {
      float a0 = sA[(tr*4+0)*33+kk];
      float a1 = sA[(tr*4+1)*33+kk];
      float a2 = sA[(tr*4+2)*33+kk];
      float a3 = sA[(tr*4+3)*33+kk];
#pragma unroll
      for (int g = 0; g < G; ++g) {
        float4 w = *(const float4*)&sW[kk*N + g*64 + tc*4];
        acc[0][g*4+0] += a0*w.x; acc[0][g*4+1] += a0*w.y; acc[0][g*4+2] += a0*w.z; acc[0][g*4+3] += a0*w.w;
        acc[1][g*4+0] += a1*w.x; acc[1][g*4+1] += a1*w.y; acc[1][g*4+2] += a1*w.z; acc[1][g*4+3] += a1*w.w;
        acc[2][g*4+0] += a2*w.x; acc[2][g*4+1] += a2*w.y; acc[2][g*4+2] += a2*w.z; acc[2][g*4+3] += a2*w.w;
        acc[3][g*4+0] += a3*w.x; acc[3][g*4+1] += a3*w.y; acc[3][g*4+2] += a3*w.z; acc[3][g*4+3] += a3*w.w;
      }
    }
    __syncthreads();
  }

#pragma unroll
  for (int i = 0; i < 4; ++i) {
    int r = r0 + tr*4 + i;
    if (r < M) {
#pragma unroll
      for (int g = 0; g < G; ++g) {
        int col = g*64 + tc*4;
        float v0 = acc[i][g*4+0], v1 = acc[i][g*4+1], v2 = acc[i][g*4+2], v3 = acc[i][g*4+3];
        if (bias) { v0 += bias[col+0]; v1 += bias[col+1]; v2 += bias[col+2]; v3 += bias[col+3]; }
        if constexpr (RELU) { v0 = fmaxf(v0,0.f); v1 = fmaxf(v1,0.f); v2 = fmaxf(v2,0.f); v3 = fmaxf(v3,0.f); }
        if constexpr (RESID) {
          float4 rv = *(const float4*)&resid[(size_t)r*N + col];
          v0 += rv.x; v1 += rv.y; v2 += rv.z; v3 += rv.w;
        }
        float4 o4; o4.x = v0; o4.y = v1; o4.z = v2; o4.w = v3;
        *(float4*)&C[(size_t)r*N + col] = o4;
      }
    }
  }
}

// ---------------- LayerNorm ----------------
__global__ void __launch_bounds__(256) k_ln(
    const float* __restrict__ x, const float* __restrict__ g, const float* __restrict__ b,
    float* __restrict__ o, int M)
{
  const int lane = threadIdx.x & 63, w = threadIdx.x >> 6;
  int rb = blockIdx.x*32 + w*8;
  for (int it = 0; it < 8; ++it) {
    int r = rb + it;
    if (r >= M) return;
    float a = x[(size_t)r*128 + lane];
    float c = x[(size_t)r*128 + 64 + lane];
    float s = a + c;
    for (int o2 = 32; o2; o2 >>= 1) s += __shfl_xor(s, o2);
    float mu = s * (1.f/128.f);
    float da = a - mu, dc = c - mu;
    float v = da*da + dc*dc;
    for (int o2 = 32; o2; o2 >>= 1) v += __shfl_xor(v, o2);
    float rs = rsqrtf(v*(1.f/128.f) + 1e-5f);
    o[(size_t)r*128 + lane]      = da*rs*g[lane]    + b[lane];
    o[(size_t)r*128 + 64 + lane] = dc*rs*g[lane+64] + b[lane+64];
  }
}

// ---------------- sampled sims (MFMA): 1024 rows x 1563 stride-64 samples ----------------
__global__ void __launch_bounds__(256) k_samp_sims(
    const unsigned short* __restrict__ kbAh, const unsigned short* __restrict__ kbAl,
    const unsigned short* __restrict__ ckh,  const unsigned short* __restrict__ ckl,
    const float* __restrict__ candn, float* __restrict__ samp)
{
  const int tid = threadIdx.x;
  const int wv = tid >> 6, lane = tid & 63;
  const int st = blockIdx.x, ch = blockIdx.y;
  const int q = lane >> 4, n16 = lane & 15;

  f32x4 acc00 = {0.f,0.f,0.f,0.f}, acc01 = {0.f,0.f,0.f,0.f};
  f32x4 acc02 = {0.f,0.f,0.f,0.f}, acc03 = {0.f,0.f,0.f,0.f};
  f32x4 acc10 = {0.f,0.f,0.f,0.f}, acc11 = {0.f,0.f,0.f,0.f};
  f32x4 acc12 = {0.f,0.f,0.f,0.f}, acc13 = {0.f,0.f,0.f,0.f};

  const int mt0 = wv*2, mt1 = wv*2 + 1;
  const size_t a0base = (size_t)(ch*8 + mt0)*2048;
  const size_t a1base = (size_t)(ch*8 + mt1)*2048;
  int s0 = st*64 + 0*16 + n16, s1 = st*64 + 1*16 + n16;
  int s2 = st*64 + 2*16 + n16, s3 = st*64 + 3*16 + n16;
  const size_t b0 = (size_t)(s0 < NSAMP ? s0*64 : 0)*128;
  const size_t b1 = (size_t)(s1 < NSAMP ? s1*64 : 0)*128;
  const size_t b2 = (size_t)(s2 < NSAMP ? s2*64 : 0)*128;
  const size_t b3 = (size_t)(s3 < NSAMP ? s3*64 : 0)*128;

#pragma unroll
  for (int s = 0; s < 4; ++s) {
    const size_t ao = (size_t)s*512 + (size_t)lane*8;
    bf16x8 ah0 = *(const bf16x8*)(kbAh + a0base + ao);
    bf16x8 ah1 = *(const bf16x8*)(kbAh + a1base + ao);
    bf16x8 al0 = *(const bf16x8*)(kbAl + a0base + ao);
    bf16x8 al1 = *(const bf16x8*)(kbAl + a1base + ao);
    const int ko = s*32 + q*8;
    bf16x8 bh0v = *(const bf16x8*)(ckh + b0 + ko);
    bf16x8 bh1v = *(const bf16x8*)(ckh + b1 + ko);
    bf16x8 bh2v = *(const bf16x8*)(ckh + b2 + ko);
    bf16x8 bh3v = *(const bf16x8*)(ckh + b3 + ko);
    bf16x8 bl0v = *(const bf16x8*)(ckl + b0 + ko);
    bf16x8 bl1v = *(const bf16x8*)(ckl + b1 + ko);
    bf16x8 bl2v = *(const bf16x8*)(ckl + b2 + ko);
    bf16x8 bl3v = *(const bf16x8*)(ckl + b3 + ko);

    MFMA16(ah0, bh0v, acc00); MFMA16(ah0, bh1v, acc01);
    MFMA16(ah0, bh2v, acc02); MFMA16(ah0, bh3v, acc03);
    MFMA16(ah1, bh0v, acc10); MFMA16(ah1, bh1v, acc11);
    MFMA16(ah1, bh2v, acc12); MFMA16(ah1, bh3v, acc13);

    MFMA16(al0, bh0v, acc00); MFMA16(al0, bh1v, acc01);
    MFMA16(al0, bh2v, acc02); MFMA16(al0, bh3v, acc03);
    MFMA16(al1, bh0v, acc10); MFMA16(al1, bh1v, acc11);
    MFMA16(al1, bh2v, acc12); MFMA16(al1, bh3v, acc13);

    MFMA16(ah0, bl0v, acc00); MFMA16(ah0, bl1v, acc01);
    MFMA16(ah0, bl2v, acc02); MFMA16(ah0, bl3v, acc03);
    MFMA16(ah1, bl0v, acc10); MFMA16(ah1, bl1v, acc11);
    MFMA16(ah1, bl2v, acc12); MFMA16(ah1, bl3v, acc13);
  }

  const int rb0 = ch*128 + mt0*16 + q*4, rb1 = ch*128 + mt1*16 + q*4;
#define EPI(SI, A0, A1) { \
    if (SI < NSAMP) { \
      float cn = candn[SI*64]; \
      samp[(size_t)(rb0+0)*SAMPP + SI] = 2.f*A0[0] - cn; \
      samp[(size_t)(rb0+1)*SAMPP + SI] = 2.f*A0[1] - cn; \
      samp[(size_t)(rb0+2)*SAMPP + SI] = 2.f*A0[2] - cn; \
      samp[(size_t)(rb0+3)*SAMPP + SI] = 2.f*A0[3] - cn; \
      samp[(size_t)(rb1+0)*SAMPP + SI] = 2.f*A1[0] - cn; \
      samp[(size_t)(rb1+1)*SAMPP + SI] = 2.f*A1[1] - cn; \
      samp[(size_t)(rb1+2)*SAMPP + SI] = 2.f*A1[2] - cn; \
      samp[(size_t)(rb1+3)*SAMPP + SI] = 2.f*A1[3] - cn; \
    } }
  EPI(s0, acc00, acc10)
  EPI(s1, acc01, acc11)
  EPI(s2, acc02, acc12)
  EPI(s3, acc03, acc13)
#undef EPI
}

// ---------------- per-row thresholds (1024 blocks) ----------------
__global__ void __launch_bounds__(256) k_sample(
    const float* __restrict__ samp, float* __restrict__ gthr, unsigned* __restrict__ gcnt)
{
  __shared__ float sv[NSAMP];
  __shared__ unsigned hist[256];
  __shared__ float wmin[4], wmax[4];
  __shared__ float s_lo, s_inv, s_w;
  const int tid = threadIdx.x, row = blockIdx.x;
  const float* S = samp + (size_t)row*SAMPP;
  float lmax = -__builtin_inff(), lmin = __builtin_inff();
  for (int i = tid; i < NSAMP; i += 256) {
    float v = S[i];
    sv[i] = v;
    lmax = fmaxf(lmax, v); lmin = fminf(lmin, v);
  }
  if (tid < 256) hist[tid] = 0;
  for (int o = 32; o; o >>= 1) {
    lmax = fmaxf(lmax, __shfl_xor(lmax, o));
    lmin = fminf(lmin, __shfl_xor(lmin, o));
  }
  if ((tid & 63) == 0) { wmax[tid>>6] = lmax; wmin[tid>>6] = lmin; }
  __syncthreads();
  if (tid == 0) {
    float hi = wmax[0], lo = wmin[0];
    for (int w = 1; w < 4; ++w) { hi = fmaxf(hi, wmax[w]); lo = fminf(lo, wmin[w]); }
    float rng = hi - lo;
    s_lo = lo;
    s_inv = (rng > 0.f) ? (256.f/rng) : 0.f;
    s_w   = (rng > 0.f) ? (rng/256.f) : 0.f;
  }
  __syncthreads();
  const float lo = s_lo, inv = s_inv;
  for (int i = tid; i < NSAMP; i += 256) {
    int b = min(max((int)((sv[i]-lo)*inv), 0), 255);
    atomicAdd(&hist[b], 1u);
  }
  __syncthreads();
  if (tid == 0) {
    unsigned cum = 0; int b = 255;
    for (; b >= 1; --b) { if (cum + hist[b] >= 24u) break; cum += hist[b]; }
    gthr[row] = lo + (float)b * s_w;
    gcnt[row*16] = 0u;
  }
}

// ---------------- sims + fused emission (one launch) ----------------
__global__ void __launch_bounds__(256) k_sims_emit(
    const unsigned short* __restrict__ kbAh, const unsigned short* __restrict__ kbAl,
    const unsigned short* __restrict__ ckh,  const unsigned short* __restrict__ ckl,
    const float* __restrict__ candn, const float* __restrict__ gthr,
    unsigned* __restrict__ gcnt, float* __restrict__ ev, int* __restrict__ ei)
{
  __shared__ float sthr[128];
  __shared__ unsigned ecnt[128];
  __shared__ float lv[128*TCAP];
  __shared__ int   li[128*TCAP];
  const int tid = threadIdx.x;
  const int wv = tid >> 6, lane = tid & 63;
  const int c0 = blockIdx.x * 64;
  const int ch = blockIdx.y;
  const int q = lane >> 4, n16 = lane & 15;

  if (tid < 128) { sthr[tid] = gthr[ch*128 + tid]; ecnt[tid] = 0; }
  __syncthreads();

  f32x4 acc00 = {0.f,0.f,0.f,0.f}, acc01 = {0.f,0.f,0.f,0.f};
  f32x4 acc02 = {0.f,0.f,0.f,0.f}, acc03 = {0.f,0.f,0.f,0.f};
  f32x4 acc10 = {0.f,0.f,0.f,0.f}, acc11 = {0.f,0.f,0.f,0.f};
  f32x4 acc12 = {0.f,0.f,0.f,0.f}, acc13 = {0.f,0.f,0.f,0.f};

  const int mt0 = wv*2, mt1 = wv*2 + 1;
  const size_t a0base = (size_t)(ch*8 + mt0)*2048;
  const size_t a1base = (size_t)(ch*8 + mt1)*2048;
  const size_t b0 = (size_t)(c0 + n16)*128;
  const size_t b1 = b0 + 16*128;
  const size_t b2 = b0 + 32*128;
  const size_t b3 = b0 + 48*128;

#pragma unroll
  for (int s = 0; s < 4; ++s) {
    const size_t ao = (size_t)s*512 + (size_t)lane*8;
    bf16x8 ah0 = *(const bf16x8*)(kbAh + a0base + ao);
    bf16x8 ah1 = *(const bf16x8*)(kbAh + a1base + ao);
    bf16x8 al0 = *(const bf16x8*)(kbAl + a0base + ao);
    bf16x8 al1 = *(const bf16x8*)(kbAl + a1base + ao);
    const int ko = s*32 + q*8;
    bf16x8 bh0v = *(const bf16x8*)(ckh + b0 + ko);
    bf16x8 bh1v = *(const bf16x8*)(ckh + b1 + ko);
    bf16x8 bh2v = *(const bf16x8*)(ckh + b2 + ko);
    bf16x8 bh3v = *(const bf16x8*)(ckh + b3 + ko);
    bf16x8 bl0v = *(const bf16x8*)(ckl + b0 + ko);
    bf16x8 bl1v = *(const bf16x8*)(ckl + b1 + ko);
    bf16x8 bl2v = *(const bf16x8*)(ckl + b2 + ko);
    bf16x8 bl3v = *(const bf16x8*)(ckl + b3 + ko);

    MFMA16(ah0, bh0v, acc00); MFMA16(ah0, bh1v, acc01);
    MFMA16(ah0, bh2v, acc02); MFMA16(ah0, bh3v, acc03);
    MFMA16(ah1, bh0v, acc10); MFMA16(ah1, bh1v, acc11);
    MFMA16(ah1, bh2v, acc12); MFMA16(ah1, bh3v, acc13);

    MFMA16(al0, bh0v, acc00); MFMA16(al0, bh1v, acc01);
    MFMA16(al0, bh2v, acc02); MFMA16(al0, bh3v, acc03);
    MFMA16(al1, bh0v, acc10); MFMA16(al1, bh1v, acc11);
    MFMA16(al1, bh2v, acc12); MFMA16(al1, bh3v, acc13);

    MFMA16(ah0, bl0v, acc00); MFMA16(ah0, bl1v, acc01);
    MFMA16(ah0, bl2v, acc02); MFMA16(ah0, bl3v, acc03);
    MFMA16(ah1, bl0v, acc10); MFMA16(ah1, bl1v, acc11);
    MFMA16(ah1, bl2v, acc12); MFMA16(ah1, bl3v, acc13);
  }

  const int rb0 = mt0*16 + q*4, rb1 = mt1*16 + q*4;
#define EPI(NT, A0, A1) { \
    int col = c0 + NT*16 + n16; \
    if (col < NCAND) { \
      float cn = candn[col]; \
      _Pragma("unroll") \
      for (int i = 0; i < 4; ++i) { \
        float v0 = 2.f*A0[i] - cn; \
        if (v0 >= sthr[rb0+i]) { \
          unsigned p = atomicAdd(&ecnt[rb0+i], 1u); \
          if (p < TCAP) { lv[(rb0+i)*TCAP + p] = v0; li[(rb0+i)*TCAP + p] = col; } \
        } \
        float v1 = 2.f*A1[i] - cn; \
        if (v1 >= sthr[rb1+i]) { \
          unsigned p = atomicAdd(&ecnt[rb1+i], 1u); \
          if (p < TCAP) { lv[(rb1+i)*TCAP + p] = v1; li[(rb1+i)*TCAP + p] = col; } \
        } \
      } \
    } }
  EPI(0, acc00, acc10)
  EPI(1, acc01, acc11)
  EPI(2, acc02, acc12)
  EPI(3, acc03, acc13)
#undef EPI
  __syncthreads();

  if (tid < 128) {
    int n = (int)min(ecnt[tid], (unsigned)TCAP);
    if (n > 0) {
      int grow = ch*128 + tid;
      unsigned base = atomicAdd(&gcnt[grow*16], (unsigned)n);
      float* EV = ev + (size_t)grow*EMCAP;
      int*   EI = ei + (size_t)grow*EMCAP;
      for (int j = 0; j < n; ++j) {
        unsigned p = base + j;
        if (p < EMCAP) { EV[p] = lv[tid*TCAP + j]; EI[p] = li[tid*TCAP + j]; }
      }
    }
  }
}

// ---------------- final top-96 + softmax + gathers (1024 blocks) ----------------
__global__ void __launch_bounds__(256) k_final(
    const float* __restrict__ ev, const int* __restrict__ ei,
    const unsigned* __restrict__ gcnt, const float* __restrict__ cand_y,
    float* __restrict__ probs, int* __restrict__ tidxg, float* __restrict__ ygath)
{
  __shared__ float sv[EMCAP];
  __shared__ unsigned hist[1024];
  __shared__ float tv[512]; __shared__ int ti[512];
  __shared__ float selv[96]; __shared__ int seli[96];
  __shared__ unsigned cnts[2];
  __shared__ float wv[4]; __shared__ int wp[4];
  __shared__ float wmin[4], wmax[4];
  __shared__ float s_lo, s_inv;
  __shared__ int sb_s, above_s;
  __shared__ float smax_s, ssum_s;

  const int tid = threadIdx.x, row = blockIdx.x;
  const int n = (int)min(gcnt[row*16], (unsigned)EMCAP);
  const float* EV = ev + (size_t)row*EMCAP;
  const int*   EI = ei + (size_t)row*EMCAP;

  if (tid < 96) { selv[tid] = -1e30f; seli[tid] = 0; }
  for (int i = tid; i < 1024; i += 256) hist[i] = 0;
  if (tid < 2) cnts[tid] = 0;

  float lmax = -__builtin_inff(), lmin = __builtin_inff();
  for (int i = tid; i < n; i += 256) {
    float v = EV[i]; sv[i] = v;
    lmax = fmaxf(lmax, v); lmin = fminf(lmin, v);
  }
  for (int o = 32; o; o >>= 1) {
    lmax = fmaxf(lmax, __shfl_xor(lmax, o));
    lmin = fminf(lmin, __shfl_xor(lmin, o));
  }
  if ((tid & 63) == 0) { wmax[tid>>6] = lmax; wmin[tid>>6] = lmin; }
  __syncthreads();
  if (tid == 0) {
    float hi = wmax[0], lo = wmin[0];
    for (int w2 = 1; w2 < 4; ++w2) { hi = fmaxf(hi, wmax[w2]); lo = fminf(lo, wmin[w2]); }
    float rng = hi - lo;
    s_lo = lo; s_inv = (rng > 0.f) ? (1024.f/rng) : 0.f;
  }
  __syncthreads();
  const float lo = s_lo, inv = s_inv;

  for (int i = tid; i < n; i += 256) {
    int b = min(max((int)((sv[i]-lo)*inv), 0), 1023);
    atomicAdd(&hist[b], 1u);
  }
  __syncthreads();
  if (tid == 0) {
    unsigned cum = 0; int b = 1023;
    for (; b >= 1; --b) { if (cum + hist[b] >= 96u) break; cum += hist[b]; }
    sb_s = b; above_s = (int)cum;
  }
  __syncthreads();
  const int sb = sb_s, above = above_s;

  for (int i = tid; i < n; i += 256) {
    float v = sv[i];
    int b = min(max((int)((v-lo)*inv), 0), 1023);
    if (b > sb) {
      unsigned p = atomicAdd(&cnts[0], 1u);
      if (p < 96u) { selv[p] = v; seli[p] = EI[i]; }
    } else if (b == sb) {
      unsigned p = atomicAdd(&cnts[1], 1u);
      if (p < 512u) { tv[p] = v; ti[p] = EI[i]; }
    }
  }
  __syncthreads();
  const int need = 96 - above;
  const int tcnt = (int)min(cnts[1], 512u);
  for (int rd = 0; rd < need; ++rd) {
    float best = -__builtin_inff(); int bp = -1;
    for (int t = tid; t < tcnt; t += 256) {
      float v = tv[t];
      if (v > best) { best = v; bp = t; }
    }
    for (int o = 32; o; o >>= 1) {
      float ob = __shfl_xor(best, o); int obp = __shfl_xor(bp, o);
      if (ob > best) { best = ob; bp = obp; }
    }
    if ((tid & 63) == 0) { wv[tid>>6] = best; wp[tid>>6] = bp; }
    __syncthreads();
    if (tid == 0) {
      float bb = wv[0]; int pp = wp[0];
      for (int w2 = 1; w2 < 4; ++w2) if (wv[w2] > bb) { bb = wv[w2]; pp = wp[w2]; }
      if (pp >= 0) { selv[above + rd] = bb; seli[above + rd] = ti[pp]; tv[pp] = -__builtin_inff(); }
    }
    __syncthreads();
  }

  if (tid == 0) {
    float m = selv[0];
    for (int i = 1; i < 96; ++i) m = fmaxf(m, selv[i]);
    smax_s = m;
  }
  __syncthreads();
  if (tid < 96) selv[tid] = expf(selv[tid] - smax_s);
  __syncthreads();
  if (tid == 0) {
    float s = 0.f;
    for (int i = 0; i < 96; ++i) s += selv[i];
    ssum_s = s;
  }
  __syncthreads();
  if (tid < 96) {
    int gi = seli[tid];
    gi = (gi >= 0 && gi < NCAND) ? gi : 0;   // defensive clamp
    probs[(size_t)row*96 + tid] = selv[tid]/ssum_s;
    tidxg[(size_t)row*96 + tid] = gi;
    ygath[(size_t)row*96 + tid] = cand_y[gi];
  }
}

// ---------------- context accumulation ----------------
__global__ void __launch_bounds__(128) k_ctx(
    const float* __restrict__ probs, const float* __restrict__ ygath,
    const float* __restrict__ t2, const float* __restrict__ x2b,
    const float* __restrict__ w_le, const float* __restrict__ b_le,
    float* __restrict__ xfinal)
{
  int bb = blockIdx.x;
  int d = threadIdx.x;
  float wle = w_le[d], ble = b_le[d];
  float acc = 0.f;
  for (int c = 0; c < 96; ++c) {
    float p = probs[(size_t)bb*96 + c];
    float y = ygath[(size_t)bb*96 + c];
    acc += p*(y*wle + ble + t2[(size_t)(bb*96 + c)*128 + d]);
  }
  xfinal[(size_t)bb*128 + d] = x2b[(size_t)bb*128 + d] + acc;
}

// ---------------- head ----------------
__global__ void __launch_bounds__(256) k_head(
    const float* __restrict__ x, const float* __restrict__ g, const float* __restrict__ b,
    const float* __restrict__ Wh, const float* __restrict__ bh,
    float* __restrict__ out, int M)
{
  const int lane = threadIdx.x & 63, w = threadIdx.x >> 6;
  int rb = blockIdx.x*32 + w*8;
  for (int it = 0; it < 8; ++it) {
    int r = rb + it;
    if (r >= M) return;
    float a = x[(size_t)r*128 + lane];
    float c = x[(size_t)r*128 + 64 + lane];
    float s = a + c;
    for (int o = 32; o; o >>= 1) s += __shfl_xor(s, o);
    float mu = s*(1.f/128.f);
    float da = a - mu, dc = c - mu;
    float v = da*da + dc*dc;
    for (int o = 32; o; o >>= 1) v += __shfl_xor(v, o);
    float rs = rsqrtf(v*(1.f/128.f) + 1e-5f);
    float l0 = fmaxf(da*rs*g[lane]    + b[lane],    0.f);
    float l1 = fmaxf(dc*rs*g[lane+64] + b[lane+64], 0.f);
    float p0 = l0*Wh[lane]     + l1*Wh[64+lane];
    float p1 = l0*Wh[128+lane] + l1*Wh[192+lane];
    for (int o = 32; o; o >>= 1) { p0 += __shfl_xor(p0, o); p1 += __shfl_xor(p1, o); }
    if (lane == 0) { out[r*2 + 0] = p0 + bh[0]; out[r*2 + 1] = p1 + bh[1]; }
  }
}

// ---------------- launcher ----------------
extern "C" void kernel_launch(void* const* d_in, const int* in_sizes, int n_in,
                              void* d_out, int out_size, void* d_ws, size_t ws_size,
                              hipStream_t stream) {
  const float* x_num   = (const float*)d_in[0];
  const float* cand_x  = (const float*)d_in[1];
  const float* cand_y  = (const float*)d_in[2];
  const float* W_in    = (const float*)d_in[3];
  const float* b_in    = (const float*)d_in[4];
  const float* enc_W1  = (const float*)d_in[5];
  const float* enc_b1  = (const float*)d_in[6];
  const float* enc_W2  = (const float*)d_in[7];
  const float* enc_b2  = (const float*)d_in[8];
  const float* mix_g   = (const float*)d_in[9];
  const float* mix_b   = (const float*)d_in[10];
  const float* W_k     = (const float*)d_in[11];
  const float* b_k     = (const float*)d_in[12];
  const float* w_le    = (const float*)d_in[13];
  const float* b_le    = (const float*)d_in[14];
  const float* W_t1    = (const float*)d_in[15];
  const float* b_t1    = (const float*)d_in[16];
  const float* W_t2    = (const float*)d_in[17];
  const float* pred_g  = (const float*)d_in[18];
  const float* pred_b  = (const float*)d_in[19];
  const float* pred_W1 = (const float*)d_in[20];
  const float* pred_b1 = (const float*)d_in[21];
  const float* pred_W2 = (const float*)d_in[22];
  const float* pred_b2 = (const float*)d_in[23];
  const float* head_g  = (const float*)d_in[24];
  const float* head_b  = (const float*)d_in[25];
  const float* W_head  = (const float*)d_in[26];
  const float* b_head  = (const float*)d_in[27];

  float* ws  = (float*)d_ws;
  float* out = (float*)d_out;

  float*          wt     = ws;
  unsigned short* Wh     = (unsigned short*)ws;
  unsigned short* Wl     = Wh + 155648;
  unsigned short* ckh    = (unsigned short*)(ws + OFF_CKH);
  unsigned short* ckl    = (unsigned short*)(ws + OFF_CKL);
  float*          candn  = ws + OFF_CANDN;
  float*          kb     = ws + OFF_KB;
  float*          x2b    = ws + OFF_X2B;
  float*          lnb    = ws + OFF_LNB;
  float*          hb     = ws + OFF_HB;
  float*          xpred  = ws + OFF_XPRED;
  float*          xfin   = ws + OFF_XFIN;
  unsigned short* kbAh   = (unsigned short*)(ws + OFF_KBA);
  unsigned short* kbAl   = kbAh + 131072;
  float*          probs  = ws + OFF_PROBS;
  int*            tidxg  = (int*)(ws + OFF_TIDX);
  float*          ygath  = ws + OFF_YG;
  float*          ev     = ws + OFF_EV;     // overlaps t2buf (sequential use)
  int*            ei     = (int*)(ws + OFF_EI);
  float*          t2buf  = ws + OFF_EV;
  float*          samp   = ws + OFF_SAMP;
  unsigned*       gcnt   = (unsigned*)(ws + OFF_GCNT);
  float*          gthr   = ws + OFF_GTHR;

  // 1) weight prep
  k_cvt_w<<<96, 256, 0, stream>>>(W_in, enc_W1, enc_W2, W_k, W_t1, W_t2, Wh, Wl);
  k_transpose<<<64, 256, 0, stream>>>(pred_W1, pred_W2, wt);
  k_pad_ck<<<16, 256, 0, stream>>>(ckh, ckl);

  // 2) batch encoder -> x2b, kb; kb -> A-frags
  k_enc_fused<true><<<BATCH/128, 256, 0, stream>>>(
      x_num, Wh, Wl, b_in, enc_b1, enc_b2, mix_g, mix_b, b_k,
      nullptr, nullptr, nullptr, x2b, kb, BATCH);
  k_cvt_kbA<<<512, 256, 0, stream>>>(kb, kbAh, kbAl);

  // 3) candidate encoder -> ckh/ckl, candn
  k_enc_fused<false><<<(NCAND+127)/128, 256, 0, stream>>>(
      cand_x, Wh, Wl, b_in, enc_b1, enc_b2, mix_g, mix_b, b_k,
      ckh, ckl, candn, nullptr, nullptr, NCAND);

  // 4) select: sampled sims -> thresholds -> fused sims+emit -> final
  k_samp_sims<<<dim3(25, 8), 256, 0, stream>>>(kbAh, kbAl, ckh, ckl, candn, samp);
  k_sample<<<BATCH, 256, 0, stream>>>(samp, gthr, gcnt);
  k_sims_emit<<<dim3(NCPAD/64, 8), 256, 0, stream>>>(kbAh, kbAl, ckh, ckl, candn, gthr, gcnt, ev, ei);
  k_final<<<BATCH, 256, 0, stream>>>(ev, ei, gcnt, cand_y, probs, tidxg, ygath);

  // 5) t-net + context
  k_tnet<<<NPAIR/64, 256, 0, stream>>>(kb, ckh, ckl, tidxg, Wh, Wl, b_t1, t2buf);
  k_ctx<<<BATCH, 128, 0, stream>>>(probs, ygath, t2buf, x2b, w_le, b_le, xfin);

  // 6) predictor block + head
  k_ln<<<(BATCH+31)/32, 256, 0, stream>>>(xfin, pred_g, pred_b, lnb, BATCH);
  k_gemm<256,true ,false><<<16, 256, 0, stream>>>(lnb, wt+WT_P1, pred_b1, nullptr, hb,    BATCH, 128);
  k_gemm<128,false,true ><<<16, 256, 0, stream>>>(hb,  wt+WT_P2, pred_b2, xfin,    xpred, BATCH, 256);
  k_head<<<(BATCH+31)/32, 256, 0, stream>>>(xpred, head_g, head_b, W_head, b_head, out, BATCH);
}